// Round 1
// baseline (3029.487 us; speedup 1.0000x reference)
//
#include <hip/hip_runtime.h>
#include <math.h>

// GCN 3-layer forward for MI355X.
// Pipeline:
//  detect idx dtype -> deg=1+indeg -> dinv=rsqrt(deg)
//  h0 = x @ W_in                         (bufA)
//  agg = scatter(h0)                     (bufB, atomics)
//  h1 = agg + dinv^2*h0 + b_in           (bufB in-place)
//  t  = h1 @ W1                          (bufA)
//  agg2 = scatter(t)                     (bufB, atomics)
//  h2 = relu(agg2 + dinv^2*t + b1)       (bufB in-place)
//  out = log_softmax(h2 @ W_out + b_out) (d_out)

#define THREADS 256

// ---- index-dtype detection: int64 arrays have high words == 0 -------------
__global__ void detect_idx64(const int* __restrict__ idx, int* __restrict__ flag) {
    int t = threadIdx.x;                       // 64 threads
    unsigned long long b = __ballot(idx[2 * t + 1] == 0);
    if (t == 0) *flag = (b == 0xFFFFFFFFFFFFFFFFull) ? 1 : 0;
}

__global__ void init_deg(float* __restrict__ deg, int N) {
    int i = blockIdx.x * blockDim.x + threadIdx.x;
    if (i < N) deg[i] = 1.0f;
}

__global__ void deg_accum(const int* __restrict__ idx, const int* __restrict__ flag,
                          float* __restrict__ deg, int E) {
    int e = blockIdx.x * blockDim.x + threadIdx.x;
    if (e >= E) return;
    int f = *flag;
    int dst = f ? idx[2 * (E + e)] : idx[E + e];
    atomicAdd(&deg[dst], 1.0f);
}

__global__ void make_dinv(float* __restrict__ deg, int N) {
    int i = blockIdx.x * blockDim.x + threadIdx.x;
    if (i < N) deg[i] = rsqrtf(deg[i]);
}

// ---- GEMM: out[N,128] = A[N,128] @ W[128,128] -----------------------------
// 64 rows x 128 cols per block, 256 threads, 8x4 microtile.
// LDS: W (64KB) + X transposed (32KB) = 96KB -> 1 block/CU.
__global__ __launch_bounds__(256) void gemm128(const float* __restrict__ A,
                                               const float* __restrict__ W,
                                               float* __restrict__ out, int N) {
    __shared__ float Wlds[128 * 128];
    __shared__ float Xt[128 * 64];   // Xt[k][r]
    int tid = threadIdx.x;
    int row0 = blockIdx.x * 64;

    // stage W (coalesced, no transpose)
    const float4* W4 = (const float4*)W;
    float4* Wl4 = (float4*)Wlds;
#pragma unroll
    for (int i = 0; i < 16; ++i) Wl4[tid + 256 * i] = W4[tid + 256 * i];

    // stage X transposed: thread covers row rr, k in [kq*32, kq*32+32)
    {
        int rr = tid >> 2;
        int kq = tid & 3;
        int gr = row0 + rr;
        const float4 z4 = make_float4(0.f, 0.f, 0.f, 0.f);
#pragma unroll
        for (int i = 0; i < 8; ++i) {
            int k = kq * 32 + i * 4;
            float4 v = (gr < N) ? *(const float4*)&A[(size_t)gr * 128 + k] : z4;
            Xt[(k + 0) * 64 + rr] = v.x;
            Xt[(k + 1) * 64 + rr] = v.y;
            Xt[(k + 2) * 64 + rr] = v.z;
            Xt[(k + 3) * 64 + rr] = v.w;
        }
    }
    __syncthreads();

    int cg = tid & 31;   // cols cg*4 .. cg*4+3
    int rg = tid >> 5;   // rows rg*8 .. rg*8+7
    float acc[8][4];
#pragma unroll
    for (int j = 0; j < 8; ++j)
#pragma unroll
        for (int c = 0; c < 4; ++c) acc[j][c] = 0.f;

    const float4* Xt4 = (const float4*)Xt;
#pragma unroll 4
    for (int k = 0; k < 128; ++k) {
        float4 w = Wl4[k * 32 + cg];
        float4 xa = Xt4[k * 16 + rg * 2];
        float4 xb = Xt4[k * 16 + rg * 2 + 1];
        float xs[8] = {xa.x, xa.y, xa.z, xa.w, xb.x, xb.y, xb.z, xb.w};
#pragma unroll
        for (int j = 0; j < 8; ++j) {
            acc[j][0] += xs[j] * w.x;
            acc[j][1] += xs[j] * w.y;
            acc[j][2] += xs[j] * w.z;
            acc[j][3] += xs[j] * w.w;
        }
    }

    float4* out4 = (float4*)out;
#pragma unroll
    for (int j = 0; j < 8; ++j) {
        int r = row0 + rg * 8 + j;
        if (r < N) {
            float4 o = make_float4(acc[j][0], acc[j][1], acc[j][2], acc[j][3]);
            out4[(size_t)r * 32 + cg] = o;
        }
    }
}

// ---- edge scatter: agg[dst] += h[src] * dinv[src]*dinv[dst] ----------------
// 32 threads per edge, float4 per thread, 4 float atomics.
__global__ __launch_bounds__(256) void scatter(const float* __restrict__ h,
                                               float* __restrict__ agg,
                                               const int* __restrict__ idx,
                                               const float* __restrict__ dinv,
                                               const int* __restrict__ flag, int E) {
    int tid = blockIdx.x * 256 + threadIdx.x;
    int e = tid >> 5;
    int l = tid & 31;
    if (e >= E) return;
    int f = *flag;
    int src, dst;
    if (f) { src = idx[2 * e]; dst = idx[2 * (E + e)]; }
    else   { src = idx[e];     dst = idx[E + e]; }
    float c = dinv[src] * dinv[dst];
    float4 v = *(const float4*)&h[(size_t)src * 128 + l * 4];
    float* o = &agg[(size_t)dst * 128 + l * 4];
    atomicAdd(o + 0, v.x * c);
    atomicAdd(o + 1, v.y * c);
    atomicAdd(o + 2, v.z * c);
    atomicAdd(o + 3, v.w * c);
}

// ---- finalize: agg = [relu](agg + dinv^2 * h + b) --------------------------
__global__ __launch_bounds__(256) void finalize(float* __restrict__ agg,
                                                const float* __restrict__ h,
                                                const float* __restrict__ dinv,
                                                const float* __restrict__ b,
                                                int N, int do_relu) {
    int i = blockIdx.x * 256 + threadIdx.x;    // over N*32 float4
    if (i >= N * 32) return;
    int node = i >> 5;
    int c4 = i & 31;
    float di = dinv[node];
    float d2 = di * di;
    float4 a = ((float4*)agg)[i];
    float4 hv = ((const float4*)h)[i];
    float4 bb = ((const float4*)b)[c4];
    float4 r;
    r.x = a.x + d2 * hv.x + bb.x;
    r.y = a.y + d2 * hv.y + bb.y;
    r.z = a.z + d2 * hv.z + bb.z;
    r.w = a.w + d2 * hv.w + bb.w;
    if (do_relu) {
        r.x = fmaxf(r.x, 0.f); r.y = fmaxf(r.y, 0.f);
        r.z = fmaxf(r.z, 0.f); r.w = fmaxf(r.w, 0.f);
    }
    ((float4*)agg)[i] = r;
}

// ---- output: log_softmax(h2 @ W_out + b_out), one wave per row -------------
__global__ __launch_bounds__(256) void out_kernel(const float* __restrict__ h2,
                                                  const float* __restrict__ Wout,
                                                  const float* __restrict__ bout,
                                                  float* __restrict__ out, int N) {
    __shared__ float rowbuf[4][128];
    int w = threadIdx.x >> 6;
    int lane = threadIdx.x & 63;
    int row = blockIdx.x * 4 + w;
    if (row >= N) return;
    // wave-local staging of the h2 row (no cross-wave sharing -> no barrier)
    rowbuf[w][lane] = h2[(size_t)row * 128 + lane];
    rowbuf[w][lane + 64] = h2[(size_t)row * 128 + 64 + lane];

    float v = -INFINITY;
    if (lane < 40) {
        float acc = 0.f;
#pragma unroll 4
        for (int k = 0; k < 128; ++k) acc += rowbuf[w][k] * Wout[k * 40 + lane];
        v = acc + bout[lane];
    }
    float m = v;
#pragma unroll
    for (int off = 32; off > 0; off >>= 1) m = fmaxf(m, __shfl_xor(m, off));
    float e = (lane < 40) ? expf(v - m) : 0.f;
    float s = e;
#pragma unroll
    for (int off = 32; off > 0; off >>= 1) s += __shfl_xor(s, off);
    float ls = logf(s);
    if (lane < 40) out[(size_t)row * 40 + lane] = v - m - ls;
}

extern "C" void kernel_launch(void* const* d_in, const int* in_sizes, int n_in,
                              void* d_out, int out_size, void* d_ws, size_t ws_size,
                              hipStream_t stream) {
    const float* x     = (const float*)d_in[0];
    const int*   idx   = (const int*)d_in[1];
    const float* W_in  = (const float*)d_in[2];
    const float* b_in  = (const float*)d_in[3];
    const float* W1    = (const float*)d_in[4];
    const float* b1    = (const float*)d_in[5];
    const float* W_out = (const float*)d_in[6];
    const float* b_out = (const float*)d_in[7];
    float* out = (float*)d_out;

    int N = in_sizes[0] / 128;
    int E = in_sizes[1] / 2;

    char* ws = (char*)d_ws;
    int* flag = (int*)ws;
    float* deg = (float*)(ws + 256);
    size_t degbytes = (((size_t)N * 4) + 255) & ~(size_t)255;
    float* bufA = (float*)(ws + 256 + degbytes);
    float* bufB = bufA + (size_t)N * 128;
    size_t featbytes = (size_t)N * 128 * sizeof(float);

    int nb_n = (N + THREADS - 1) / THREADS;
    int nb_e = (E + THREADS - 1) / THREADS;
    int nb_g = (N + 63) / 64;
    int nb_s = (int)(((long long)E * 32 + THREADS - 1) / THREADS);
    int nb_f = (N * 32 + THREADS - 1) / THREADS;
    int nb_o = (N + 3) / 4;

    detect_idx64<<<1, 64, 0, stream>>>(idx, flag);
    init_deg<<<nb_n, THREADS, 0, stream>>>(deg, N);
    deg_accum<<<nb_e, THREADS, 0, stream>>>(idx, flag, deg, E);
    make_dinv<<<nb_n, THREADS, 0, stream>>>(deg, N);   // deg now holds dinv

    // layer 1
    gemm128<<<nb_g, THREADS, 0, stream>>>(x, W_in, bufA, N);          // h0
    hipMemsetAsync(bufB, 0, featbytes, stream);
    scatter<<<nb_s, THREADS, 0, stream>>>(bufA, bufB, idx, deg, flag, E);
    finalize<<<nb_f, THREADS, 0, stream>>>(bufB, bufA, deg, b_in, N, 0);  // h1 in bufB

    // layer 2
    gemm128<<<nb_g, THREADS, 0, stream>>>(bufB, W1, bufA, N);         // t
    hipMemsetAsync(bufB, 0, featbytes, stream);
    scatter<<<nb_s, THREADS, 0, stream>>>(bufA, bufB, idx, deg, flag, E);
    finalize<<<nb_f, THREADS, 0, stream>>>(bufB, bufA, deg, b1, N, 1);    // h2 in bufB

    // output layer + log_softmax
    out_kernel<<<nb_o, THREADS, 0, stream>>>(bufB, W_out, b_out, out, N);
}

// Round 2
// 527.229 us; speedup vs baseline: 5.7461x; 5.7461x over previous
//
#include <hip/hip_runtime.h>
#include <math.h>

// GCN 3-layer forward for MI355X — round 2: CSR gather instead of atomic scatter.
// Pipeline:
//  detect idx dtype
//  cnt[dst]++ (int histogram)            -> also gives degree
//  scan: rowstart/cursor/dinv            (single block)
//  fill: srcs[cursor[dst]++] = src       (counting sort by dst)
//  h0 = x @ W_in                         (bufA)
//  h1 = agg(h0) + dinv^2*h0 + b_in       (bufB, one wave/node, no atomics)
//  t  = h1 @ W1                          (bufA)
//  h2 = relu(agg(t) + dinv^2*t + b1)     (bufB)
//  out = log_softmax(h2 @ W_out + b_out) (d_out)

#define THREADS 256

// ---- index-dtype detection: int64 arrays have high words == 0 -------------
__global__ void detect_idx64(const int* __restrict__ idx, int* __restrict__ flag) {
    int t = threadIdx.x;                       // 64 threads
    unsigned long long b = __ballot(idx[2 * t + 1] == 0);
    if (t == 0) *flag = (b == 0xFFFFFFFFFFFFFFFFull) ? 1 : 0;
}

// ---- histogram of dst (counts; also degree-1) ------------------------------
__global__ void hist_dst(const int* __restrict__ idx, const int* __restrict__ flag,
                         int* __restrict__ cnt, int E) {
    int e = blockIdx.x * blockDim.x + threadIdx.x;
    if (e >= E) return;
    int f = *flag;
    int dst = f ? idx[2 * (E + e)] : idx[E + e];
    atomicAdd(&cnt[dst], 1);
}

// ---- single-block scan: rowstart (exclusive), cursor (=rowstart, reuses cnt),
//      dinv = rsqrt(1+cnt) ---------------------------------------------------
__global__ __launch_bounds__(1024) void scan_csr(int* __restrict__ cnt,
                                                 int* __restrict__ rowstart,
                                                 float* __restrict__ dinv, int N) {
    __shared__ int wtot[16];
    __shared__ int woff[17];
    __shared__ int carry;
    int tid = threadIdx.x;
    int lane = tid & 63, w = tid >> 6;
    if (tid == 0) carry = 0;
    __syncthreads();
    for (int base = 0; base < N; base += 1024) {
        int i = base + tid;
        int v = (i < N) ? cnt[i] : 0;
        int s = v;
#pragma unroll
        for (int off = 1; off < 64; off <<= 1) {
            int t = __shfl_up(s, off);
            if (lane >= off) s += t;
        }
        if (lane == 63) wtot[w] = s;
        __syncthreads();
        if (tid == 0) {
            int run = 0;
#pragma unroll
            for (int k = 0; k < 16; ++k) { woff[k] = run; run += wtot[k]; }
            woff[16] = run;
        }
        __syncthreads();
        int excl = carry + woff[w] + (s - v);
        if (i < N) {
            rowstart[i] = excl;
            cnt[i] = excl;                       // becomes cursor
            dinv[i] = rsqrtf(1.0f + (float)v);
        }
        __syncthreads();
        if (tid == 0) carry += woff[16];
        __syncthreads();
    }
    if (tid == 0) rowstart[N] = carry;
}

// ---- counting-sort fill: srcs grouped by dst -------------------------------
__global__ void fill_csr(const int* __restrict__ idx, const int* __restrict__ flag,
                         int* __restrict__ cursor, int* __restrict__ srcs, int E) {
    int e = blockIdx.x * blockDim.x + threadIdx.x;
    if (e >= E) return;
    int f = *flag;
    int src, dst;
    if (f) { src = idx[2 * e]; dst = idx[2 * (E + e)]; }
    else   { src = idx[e];     dst = idx[E + e]; }
    int pos = atomicAdd(&cursor[dst], 1);
    srcs[pos] = src;
}

// ---- GEMM: out[N,128] = A[N,128] @ W[128,128] -----------------------------
__global__ __launch_bounds__(256) void gemm128(const float* __restrict__ A,
                                               const float* __restrict__ W,
                                               float* __restrict__ out, int N) {
    __shared__ float Wlds[128 * 128];
    __shared__ float Xt[128 * 64];   // Xt[k][r]
    int tid = threadIdx.x;
    int row0 = blockIdx.x * 64;

    const float4* W4 = (const float4*)W;
    float4* Wl4 = (float4*)Wlds;
#pragma unroll
    for (int i = 0; i < 16; ++i) Wl4[tid + 256 * i] = W4[tid + 256 * i];

    {
        int rr = tid >> 2;
        int kq = tid & 3;
        int gr = row0 + rr;
        const float4 z4 = make_float4(0.f, 0.f, 0.f, 0.f);
#pragma unroll
        for (int i = 0; i < 8; ++i) {
            int k = kq * 32 + i * 4;
            float4 v = (gr < N) ? *(const float4*)&A[(size_t)gr * 128 + k] : z4;
            Xt[(k + 0) * 64 + rr] = v.x;
            Xt[(k + 1) * 64 + rr] = v.y;
            Xt[(k + 2) * 64 + rr] = v.z;
            Xt[(k + 3) * 64 + rr] = v.w;
        }
    }
    __syncthreads();

    int cg = tid & 31;
    int rg = tid >> 5;
    float acc[8][4];
#pragma unroll
    for (int j = 0; j < 8; ++j)
#pragma unroll
        for (int c = 0; c < 4; ++c) acc[j][c] = 0.f;

    const float4* Xt4 = (const float4*)Xt;
#pragma unroll 4
    for (int k = 0; k < 128; ++k) {
        float4 w = Wl4[k * 32 + cg];
        float4 xa = Xt4[k * 16 + rg * 2];
        float4 xb = Xt4[k * 16 + rg * 2 + 1];
        float xs[8] = {xa.x, xa.y, xa.z, xa.w, xb.x, xb.y, xb.z, xb.w};
#pragma unroll
        for (int j = 0; j < 8; ++j) {
            acc[j][0] += xs[j] * w.x;
            acc[j][1] += xs[j] * w.y;
            acc[j][2] += xs[j] * w.z;
            acc[j][3] += xs[j] * w.w;
        }
    }

    float4* out4 = (float4*)out;
#pragma unroll
    for (int j = 0; j < 8; ++j) {
        int r = row0 + rg * 8 + j;
        if (r < N) {
            float4 o = make_float4(acc[j][0], acc[j][1], acc[j][2], acc[j][3]);
            out4[(size_t)r * 32 + cg] = o;
        }
    }
}

// ---- aggregation: one wave per node, gather h[src], fused self-loop+bias ----
__global__ __launch_bounds__(256) void agg_node(const float* __restrict__ h,
                                                const int* __restrict__ rowstart,
                                                const int* __restrict__ srcs,
                                                const float* __restrict__ dinv,
                                                const float* __restrict__ b,
                                                float* __restrict__ out,
                                                int N, int do_relu) {
    int w = threadIdx.x >> 6, lane = threadIdx.x & 63;
    int node = blockIdx.x * 4 + w;
    if (node >= N) return;
    int beg = rowstart[node], end = rowstart[node + 1];
    float dn = dinv[node];
    const float2* h2 = (const float2*)h;
    float ax = 0.f, ay = 0.f;
    for (int j0 = beg; j0 < end; j0 += 64) {
        int myj = j0 + lane;
        int ms = 0;
        float md = 0.f;
        if (myj < end) { ms = srcs[myj]; md = dinv[ms]; }
        int m = min(64, end - j0);
        for (int k = 0; k < m; ++k) {
            int s = __shfl(ms, k);
            float c = dn * __shfl(md, k);
            float2 v = h2[(size_t)s * 64 + lane];
            ax += c * v.x;
            ay += c * v.y;
        }
    }
    float2 self = h2[(size_t)node * 64 + lane];
    float d2 = dn * dn;
    float2 bb = ((const float2*)b)[lane];
    float rx = ax + d2 * self.x + bb.x;
    float ry = ay + d2 * self.y + bb.y;
    if (do_relu) { rx = fmaxf(rx, 0.f); ry = fmaxf(ry, 0.f); }
    ((float2*)out)[(size_t)node * 64 + lane] = make_float2(rx, ry);
}

// ---- output: log_softmax(h2 @ W_out + b_out), one wave per row -------------
__global__ __launch_bounds__(256) void out_kernel(const float* __restrict__ h2,
                                                  const float* __restrict__ Wout,
                                                  const float* __restrict__ bout,
                                                  float* __restrict__ out, int N) {
    __shared__ float rowbuf[4][128];
    int w = threadIdx.x >> 6;
    int lane = threadIdx.x & 63;
    int row = blockIdx.x * 4 + w;
    if (row >= N) return;
    rowbuf[w][lane] = h2[(size_t)row * 128 + lane];
    rowbuf[w][lane + 64] = h2[(size_t)row * 128 + 64 + lane];

    float v = -INFINITY;
    if (lane < 40) {
        float acc = 0.f;
#pragma unroll 4
        for (int k = 0; k < 128; ++k) acc += rowbuf[w][k] * Wout[k * 40 + lane];
        v = acc + bout[lane];
    }
    float m = v;
#pragma unroll
    for (int off = 32; off > 0; off >>= 1) m = fmaxf(m, __shfl_xor(m, off));
    float e = (lane < 40) ? expf(v - m) : 0.f;
    float s = e;
#pragma unroll
    for (int off = 32; off > 0; off >>= 1) s += __shfl_xor(s, off);
    float ls = logf(s);
    if (lane < 40) out[(size_t)row * 40 + lane] = v - m - ls;
}

static inline size_t al256(size_t x) { return (x + 255) & ~(size_t)255; }

extern "C" void kernel_launch(void* const* d_in, const int* in_sizes, int n_in,
                              void* d_out, int out_size, void* d_ws, size_t ws_size,
                              hipStream_t stream) {
    const float* x     = (const float*)d_in[0];
    const int*   idx   = (const int*)d_in[1];
    const float* W_in  = (const float*)d_in[2];
    const float* b_in  = (const float*)d_in[3];
    const float* W1    = (const float*)d_in[4];
    const float* b1    = (const float*)d_in[5];
    const float* W_out = (const float*)d_in[6];
    const float* b_out = (const float*)d_in[7];
    float* out = (float*)d_out;

    int N = in_sizes[0] / 128;
    int E = in_sizes[1] / 2;

    char* ws = (char*)d_ws;
    size_t off = 0;
    int* flag = (int*)(ws + off);          off += 256;
    int* cnt  = (int*)(ws + off);          off += al256((size_t)N * 4);        // cnt -> cursor
    int* rowstart = (int*)(ws + off);      off += al256((size_t)(N + 1) * 4);
    float* dinv = (float*)(ws + off);      off += al256((size_t)N * 4);
    int* srcs = (int*)(ws + off);          off += al256((size_t)E * 4);
    float* bufA = (float*)(ws + off);      off += (size_t)N * 128 * 4;
    float* bufB = (float*)(ws + off);

    int nb_e = (E + THREADS - 1) / THREADS;
    int nb_g = (N + 63) / 64;
    int nb_a = (N + 3) / 4;

    detect_idx64<<<1, 64, 0, stream>>>(idx, flag);
    hipMemsetAsync(cnt, 0, (size_t)N * 4, stream);
    hist_dst<<<nb_e, THREADS, 0, stream>>>(idx, flag, cnt, E);
    scan_csr<<<1, 1024, 0, stream>>>(cnt, rowstart, dinv, N);
    fill_csr<<<nb_e, THREADS, 0, stream>>>(idx, flag, cnt, srcs, E);

    // layer 1
    gemm128<<<nb_g, THREADS, 0, stream>>>(x, W_in, bufA, N);                     // h0
    agg_node<<<nb_a, THREADS, 0, stream>>>(bufA, rowstart, srcs, dinv, b_in,
                                           bufB, N, 0);                          // h1
    // layer 2
    gemm128<<<nb_g, THREADS, 0, stream>>>(bufB, W1, bufA, N);                    // t
    agg_node<<<nb_a, THREADS, 0, stream>>>(bufA, rowstart, srcs, dinv, b1,
                                           bufB, N, 1);                          // h2
    // output layer + log_softmax
    out_kernel<<<nb_a, THREADS, 0, stream>>>(bufB, W_out, b_out, out, N);
}

// Round 4
// 405.475 us; speedup vs baseline: 7.4715x; 1.3003x over previous
//
#include <hip/hip_runtime.h>
#include <math.h>

// GCN 3-layer forward, round 3 (resubmit): bf16 activations (fp32 math),
// parallel scan, 8x8-microtile GEMM, 2-edges-per-wave bf16 gather aggregation.
// Dataflow (B0/B1 are bf16 [N,128] buffers):
//  gemm1: x(f32) @ W_in -> B0 (h0)
//  agg1 : gather(B0) + self + b_in -> B1 (h1)
//  gemm2: B1 @ W1 -> B0 (t)
//  agg2 : gather(B0) + self + b1, relu -> B1 (h2)
//  out  : log_softmax(B1 @ W_out + b_out) -> d_out (f32)

#define THREADS 256

__device__ __forceinline__ float b2f(unsigned int lo16) {
    return __uint_as_float(lo16 << 16);
}
__device__ __forceinline__ unsigned short f2b(float f) {
    unsigned int u = __float_as_uint(f);
    u += 0x7FFFu + ((u >> 16) & 1u);   // RNE
    return (unsigned short)(u >> 16);
}

// ---- index-dtype detection: int64 arrays have high words == 0 -------------
__global__ void detect_idx64(const int* __restrict__ idx, int* __restrict__ flag) {
    int t = threadIdx.x;  // 64 threads
    unsigned long long b = __ballot(idx[2 * t + 1] == 0);
    if (t == 0) *flag = (b == 0xFFFFFFFFFFFFFFFFull) ? 1 : 0;
}

// ---- histogram of dst ------------------------------------------------------
__global__ void hist_dst(const int* __restrict__ idx, const int* __restrict__ flag,
                         int* __restrict__ cnt, int E) {
    int e = blockIdx.x * blockDim.x + threadIdx.x;
    if (e >= E) return;
    int f = *flag;
    int dst = f ? idx[2 * (E + e)] : idx[E + e];
    atomicAdd(&cnt[dst], 1);
}

// ---- parallel scan (3 kernels) --------------------------------------------
__global__ __launch_bounds__(256) void scanA(const int* __restrict__ cnt,
                                             int* __restrict__ bsum, int N) {
    __shared__ int wt[4];
    int tid = threadIdx.x, lane = tid & 63, w = tid >> 6;
    int i = blockIdx.x * 256 + tid;
    int v = (i < N) ? cnt[i] : 0;
    int s = v;
#pragma unroll
    for (int off = 1; off < 64; off <<= 1) {
        int t = __shfl_up(s, off);
        if (lane >= off) s += t;
    }
    if (lane == 63) wt[w] = s;
    __syncthreads();
    if (tid == 0) bsum[blockIdx.x] = wt[0] + wt[1] + wt[2] + wt[3];
}

__global__ __launch_bounds__(256) void scanB(int* __restrict__ bsum,
                                             int* __restrict__ boff,
                                             int* __restrict__ rowstart,
                                             int nb, int N) {
    __shared__ int wt[4];
    __shared__ int wo[5];
    int tid = threadIdx.x, lane = tid & 63, w = tid >> 6;
    int v = (tid < nb) ? bsum[tid] : 0;
    int s = v;
#pragma unroll
    for (int off = 1; off < 64; off <<= 1) {
        int t = __shfl_up(s, off);
        if (lane >= off) s += t;
    }
    if (lane == 63) wt[w] = s;
    __syncthreads();
    if (tid == 0) {
        int run = 0;
#pragma unroll
        for (int k = 0; k < 4; ++k) { wo[k] = run; run += wt[k]; }
        wo[4] = run;
    }
    __syncthreads();
    if (tid < nb) boff[tid] = wo[w] + s - v;
    if (tid == 0) rowstart[N] = wo[4];
}

__global__ __launch_bounds__(256) void scanC(int* __restrict__ cnt,
                                             const int* __restrict__ boff,
                                             int* __restrict__ rowstart,
                                             float* __restrict__ dinv, int N) {
    __shared__ int wt[4];
    __shared__ int wo[4];
    int tid = threadIdx.x, lane = tid & 63, w = tid >> 6;
    int i = blockIdx.x * 256 + tid;
    int v = (i < N) ? cnt[i] : 0;
    int s = v;
#pragma unroll
    for (int off = 1; off < 64; off <<= 1) {
        int t = __shfl_up(s, off);
        if (lane >= off) s += t;
    }
    if (lane == 63) wt[w] = s;
    __syncthreads();
    if (tid == 0) {
        int run = 0;
#pragma unroll
        for (int k = 0; k < 4; ++k) { wo[k] = run; run += wt[k]; }
    }
    __syncthreads();
    if (i < N) {
        int excl = boff[blockIdx.x] + wo[w] + (s - v);
        rowstart[i] = excl;
        cnt[i] = excl;  // becomes cursor
        dinv[i] = rsqrtf(1.0f + (float)v);
    }
}

// ---- counting-sort fill ----------------------------------------------------
__global__ void fill_csr(const int* __restrict__ idx, const int* __restrict__ flag,
                         int* __restrict__ cursor, int* __restrict__ srcs, int E) {
    int e = blockIdx.x * blockDim.x + threadIdx.x;
    if (e >= E) return;
    int f = *flag;
    int src, dst;
    if (f) { src = idx[2 * e]; dst = idx[2 * (E + e)]; }
    else   { src = idx[e];     dst = idx[E + e]; }
    int pos = atomicAdd(&cursor[dst], 1);
    srcs[pos] = src;
}

// ---- GEMM: out_bf16[N,128] = A[N,128] @ W[128,128] -------------------------
// 128x128 tile, 256 threads, 8x8 split microtile. LDS 128 KB -> 1 block/CU.
template <int ABF>
__global__ __launch_bounds__(256) void gemm_t(const void* __restrict__ Ap,
                                              const float* __restrict__ W,
                                              unsigned short* __restrict__ outb,
                                              int N) {
    __shared__ float Wl[128 * 128];
    __shared__ float Xt[128 * 128];  // Xt[k][r]
    int tid = threadIdx.x;
    int row0 = blockIdx.x * 128;

    const float4* W4 = (const float4*)W;
    float4* Wl4 = (float4*)Wl;
#pragma unroll
    for (int i = 0; i < 16; ++i) Wl4[tid + 256 * i] = W4[tid + 256 * i];

    {
        int r = tid >> 1, kh = tid & 1;
        int gr = row0 + r;
#pragma unroll
        for (int i = 0; i < 16; ++i) {
            int k = kh * 64 + i * 4;
            float f0, f1, f2, f3;
            if (gr < N) {
                if (ABF) {
                    // 4 bf16 per uint2 (8B); index = gr*32 + k/4
                    uint2 q = ((const uint2*)Ap)[(size_t)gr * 32 + (k >> 2)];
                    f0 = b2f(q.x & 0xFFFFu); f1 = b2f(q.x >> 16);
                    f2 = b2f(q.y & 0xFFFFu); f3 = b2f(q.y >> 16);
                } else {
                    float4 v = ((const float4*)Ap)[(size_t)gr * 32 + (k >> 2)];
                    f0 = v.x; f1 = v.y; f2 = v.z; f3 = v.w;
                }
            } else {
                f0 = f1 = f2 = f3 = 0.f;
            }
            Xt[(k + 0) * 128 + r] = f0;
            Xt[(k + 1) * 128 + r] = f1;
            Xt[(k + 2) * 128 + r] = f2;
            Xt[(k + 3) * 128 + r] = f3;
        }
    }
    __syncthreads();

    int cg = tid & 15;   // cols {4cg..4cg+3} u {64+4cg..64+4cg+3}
    int rg = tid >> 4;   // rows {4rg..4rg+3} u {64+4rg..64+4rg+3}
    float acc[8][8];
#pragma unroll
    for (int i = 0; i < 8; ++i)
#pragma unroll
        for (int j = 0; j < 8; ++j) acc[i][j] = 0.f;

    const float4* Xt4 = (const float4*)Xt;
#pragma unroll 2
    for (int k = 0; k < 128; ++k) {
        float4 wa = Wl4[k * 32 + cg];
        float4 wb = Wl4[k * 32 + 16 + cg];
        float4 xa = Xt4[k * 32 + rg];
        float4 xb = Xt4[k * 32 + 16 + rg];
        float xs[8] = {xa.x, xa.y, xa.z, xa.w, xb.x, xb.y, xb.z, xb.w};
        float ws[8] = {wa.x, wa.y, wa.z, wa.w, wb.x, wb.y, wb.z, wb.w};
#pragma unroll
        for (int i = 0; i < 8; ++i)
#pragma unroll
            for (int j = 0; j < 8; ++j) acc[i][j] += xs[i] * ws[j];
    }

    ushort4* out4 = (ushort4*)outb;
#pragma unroll
    for (int i = 0; i < 8; ++i) {
        int r = row0 + ((i < 4) ? (rg * 4 + i) : (64 + rg * 4 + (i - 4)));
        if (r < N) {
            ushort4 oa, ob;
            oa.x = f2b(acc[i][0]); oa.y = f2b(acc[i][1]);
            oa.z = f2b(acc[i][2]); oa.w = f2b(acc[i][3]);
            ob.x = f2b(acc[i][4]); ob.y = f2b(acc[i][5]);
            ob.z = f2b(acc[i][6]); ob.w = f2b(acc[i][7]);
            out4[(size_t)r * 32 + cg] = oa;
            out4[(size_t)r * 32 + 16 + cg] = ob;
        }
    }
}

// ---- aggregation: one wave/node, bf16 gather, 2 edges per iteration --------
// lanes 0-31 handle even edges, 32-63 odd edges; feature quad = (lane&31)*4.
__global__ __launch_bounds__(256) void agg_node(const unsigned short* __restrict__ hb,
                                                const int* __restrict__ rowstart,
                                                const int* __restrict__ srcs,
                                                const float* __restrict__ dinv,
                                                const float* __restrict__ b,
                                                unsigned short* __restrict__ outb,
                                                int N, int do_relu) {
    int w = threadIdx.x >> 6, lane = threadIdx.x & 63;
    int node = blockIdx.x * 4 + w;
    if (node >= N) return;
    int beg = rowstart[node], end = rowstart[node + 1];
    float dn = dinv[node];
    int half = lane >> 5;
    int q = lane & 31;
    const uint2* hb4 = (const uint2*)hb;  // 4 bf16 per uint2
    float a0 = 0.f, a1 = 0.f, a2 = 0.f, a3 = 0.f;

    for (int j0 = beg; j0 < end; j0 += 64) {
        int myj = j0 + lane;
        int ms = 0;
        float md = 0.f;
        if (myj < end) { ms = srcs[myj]; md = dinv[ms]; }
        int m = min(64, end - j0);
        for (int k = 0; k < m; k += 2) {
            int idx2 = k + half;            // may be ==m when m odd: md=0 there
            int s = __shfl(ms, idx2);
            float c = dn * __shfl(md, idx2);
            uint2 v = hb4[(size_t)s * 32 + q];
            a0 += c * b2f(v.x & 0xFFFFu);
            a1 += c * b2f(v.x >> 16);
            a2 += c * b2f(v.y & 0xFFFFu);
            a3 += c * b2f(v.y >> 16);
        }
    }
    // combine even/odd halves
    a0 += __shfl_xor(a0, 32);
    a1 += __shfl_xor(a1, 32);
    a2 += __shfl_xor(a2, 32);
    a3 += __shfl_xor(a3, 32);

    if (half == 0) {
        uint2 sv = hb4[(size_t)node * 32 + q];
        float d2 = dn * dn;
        float4 bb = ((const float4*)b)[q];
        float r0 = a0 + d2 * b2f(sv.x & 0xFFFFu) + bb.x;
        float r1 = a1 + d2 * b2f(sv.x >> 16) + bb.y;
        float r2 = a2 + d2 * b2f(sv.y & 0xFFFFu) + bb.z;
        float r3 = a3 + d2 * b2f(sv.y >> 16) + bb.w;
        if (do_relu) {
            r0 = fmaxf(r0, 0.f); r1 = fmaxf(r1, 0.f);
            r2 = fmaxf(r2, 0.f); r3 = fmaxf(r3, 0.f);
        }
        ushort4 o;
        o.x = f2b(r0); o.y = f2b(r1); o.z = f2b(r2); o.w = f2b(r3);
        ((ushort4*)outb)[(size_t)node * 32 + q] = o;
    }
}

// ---- output: log_softmax(h2 @ W_out + b_out) -------------------------------
__global__ __launch_bounds__(256) void out_kernel(const unsigned short* __restrict__ h2b,
                                                  const float* __restrict__ Wout,
                                                  const float* __restrict__ bout,
                                                  float* __restrict__ out,
                                                  int N, int nblocks) {
    __shared__ float Wl[128 * 40];
    __shared__ float bl[40];
    __shared__ float rowbuf[4][128];
    int tid = threadIdx.x;
    for (int i = tid; i < 128 * 40; i += 256) Wl[i] = Wout[i];
    if (tid < 40) bl[tid] = bout[tid];
    __syncthreads();
    int w = tid >> 6, lane = tid & 63;
    for (int row = blockIdx.x * 4 + w; row < N; row += nblocks * 4) {
        unsigned int u = ((const unsigned int*)h2b)[(size_t)row * 64 + lane];
        rowbuf[w][2 * lane] = b2f(u & 0xFFFFu);
        rowbuf[w][2 * lane + 1] = b2f(u >> 16);
        float v = -INFINITY;
        if (lane < 40) {
            float acc = 0.f;
#pragma unroll 4
            for (int k = 0; k < 128; ++k) acc += rowbuf[w][k] * Wl[k * 40 + lane];
            v = acc + bl[lane];
        }
        float m = v;
#pragma unroll
        for (int off = 32; off > 0; off >>= 1) m = fmaxf(m, __shfl_xor(m, off));
        float e = (lane < 40) ? expf(v - m) : 0.f;
        float s = e;
#pragma unroll
        for (int off = 32; off > 0; off >>= 1) s += __shfl_xor(s, off);
        float ls = logf(s);
        if (lane < 40) out[(size_t)row * 40 + lane] = v - m - ls;
    }
}

static inline size_t al256(size_t x) { return (x + 255) & ~(size_t)255; }

extern "C" void kernel_launch(void* const* d_in, const int* in_sizes, int n_in,
                              void* d_out, int out_size, void* d_ws, size_t ws_size,
                              hipStream_t stream) {
    const float* x     = (const float*)d_in[0];
    const int*   idx   = (const int*)d_in[1];
    const float* W_in  = (const float*)d_in[2];
    const float* b_in  = (const float*)d_in[3];
    const float* W1    = (const float*)d_in[4];
    const float* b1    = (const float*)d_in[5];
    const float* W_out = (const float*)d_in[6];
    const float* b_out = (const float*)d_in[7];
    float* out = (float*)d_out;

    int N = in_sizes[0] / 128;
    int E = in_sizes[1] / 2;

    char* ws = (char*)d_ws;
    size_t off = 0;
    int* flag = (int*)(ws + off);       off += 256;
    int* cnt = (int*)(ws + off);        off += al256((size_t)N * 4);
    int* rowstart = (int*)(ws + off);   off += al256((size_t)(N + 1) * 4);
    float* dinv = (float*)(ws + off);   off += al256((size_t)N * 4);
    int* srcs = (int*)(ws + off);       off += al256((size_t)E * 4);
    int* bsum = (int*)(ws + off);       off += 2048;
    int* boff = (int*)(ws + off);       off += 2048;
    unsigned short* B0 = (unsigned short*)(ws + off);  off += (size_t)N * 128 * 2;
    unsigned short* B1 = (unsigned short*)(ws + off);

    int nb_e = (E + THREADS - 1) / THREADS;
    int nb_n = (N + THREADS - 1) / THREADS;   // scan blocks (<=256 for N<=65536)
    int nb_g = (N + 127) / 128;
    int nb_a = (N + 3) / 4;
    int nb_o = 512;

    detect_idx64<<<1, 64, 0, stream>>>(idx, flag);
    hipMemsetAsync(cnt, 0, (size_t)N * 4, stream);
    hist_dst<<<nb_e, THREADS, 0, stream>>>(idx, flag, cnt, E);
    scanA<<<nb_n, THREADS, 0, stream>>>(cnt, bsum, N);
    scanB<<<1, THREADS, 0, stream>>>(bsum, boff, rowstart, nb_n, N);
    scanC<<<nb_n, THREADS, 0, stream>>>(cnt, boff, rowstart, dinv, N);
    fill_csr<<<nb_e, THREADS, 0, stream>>>(idx, flag, cnt, srcs, E);

    // layer 1
    gemm_t<0><<<nb_g, THREADS, 0, stream>>>(x, W_in, B0, N);                  // h0
    agg_node<<<nb_a, THREADS, 0, stream>>>(B0, rowstart, srcs, dinv, b_in,
                                           B1, N, 0);                         // h1
    // layer 2
    gemm_t<1><<<nb_g, THREADS, 0, stream>>>(B1, W1, B0, N);                   // t
    agg_node<<<nb_a, THREADS, 0, stream>>>(B0, rowstart, srcs, dinv, b1,
                                           B1, N, 1);                         // h2
    // output layer + log_softmax
    out_kernel<<<nb_o, THREADS, 0, stream>>>(B1, W_out, b_out, out, N, nb_o);
}

// Round 5
// 365.763 us; speedup vs baseline: 8.2827x; 1.1086x over previous
//
#include <hip/hip_runtime.h>
#include <math.h>

// GCN 3-layer forward, round 5: out_kernel -> tiled GEMM + fused log_softmax.
// Dataflow (B0/B1 are bf16 [N,128] buffers):
//  gemm1: x(f32) @ W_in -> B0 (h0)
//  agg1 : gather(B0) + self + b_in -> B1 (h1)
//  gemm2: B1 @ W1 -> B0 (t)
//  agg2 : gather(B0) + self + b1, relu -> B1 (h2)
//  out  : log_softmax(B1 @ W_out + b_out) -> d_out (f32)   [new tiled kernel]

#define THREADS 256

__device__ __forceinline__ float b2f(unsigned int lo16) {
    return __uint_as_float(lo16 << 16);
}
__device__ __forceinline__ unsigned short f2b(float f) {
    unsigned int u = __float_as_uint(f);
    u += 0x7FFFu + ((u >> 16) & 1u);   // RNE
    return (unsigned short)(u >> 16);
}

// ---- index-dtype detection: int64 arrays have high words == 0 -------------
__global__ void detect_idx64(const int* __restrict__ idx, int* __restrict__ flag) {
    int t = threadIdx.x;  // 64 threads
    unsigned long long b = __ballot(idx[2 * t + 1] == 0);
    if (t == 0) *flag = (b == 0xFFFFFFFFFFFFFFFFull) ? 1 : 0;
}

// ---- histogram of dst ------------------------------------------------------
__global__ void hist_dst(const int* __restrict__ idx, const int* __restrict__ flag,
                         int* __restrict__ cnt, int E) {
    int e = blockIdx.x * blockDim.x + threadIdx.x;
    if (e >= E) return;
    int f = *flag;
    int dst = f ? idx[2 * (E + e)] : idx[E + e];
    atomicAdd(&cnt[dst], 1);
}

// ---- parallel scan (3 kernels) --------------------------------------------
__global__ __launch_bounds__(256) void scanA(const int* __restrict__ cnt,
                                             int* __restrict__ bsum, int N) {
    __shared__ int wt[4];
    int tid = threadIdx.x, lane = tid & 63, w = tid >> 6;
    int i = blockIdx.x * 256 + tid;
    int v = (i < N) ? cnt[i] : 0;
    int s = v;
#pragma unroll
    for (int off = 1; off < 64; off <<= 1) {
        int t = __shfl_up(s, off);
        if (lane >= off) s += t;
    }
    if (lane == 63) wt[w] = s;
    __syncthreads();
    if (tid == 0) bsum[blockIdx.x] = wt[0] + wt[1] + wt[2] + wt[3];
}

__global__ __launch_bounds__(256) void scanB(int* __restrict__ bsum,
                                             int* __restrict__ boff,
                                             int* __restrict__ rowstart,
                                             int nb, int N) {
    __shared__ int wt[4];
    __shared__ int wo[5];
    int tid = threadIdx.x, lane = tid & 63, w = tid >> 6;
    int v = (tid < nb) ? bsum[tid] : 0;
    int s = v;
#pragma unroll
    for (int off = 1; off < 64; off <<= 1) {
        int t = __shfl_up(s, off);
        if (lane >= off) s += t;
    }
    if (lane == 63) wt[w] = s;
    __syncthreads();
    if (tid == 0) {
        int run = 0;
#pragma unroll
        for (int k = 0; k < 4; ++k) { wo[k] = run; run += wt[k]; }
        wo[4] = run;
    }
    __syncthreads();
    if (tid < nb) boff[tid] = wo[w] + s - v;
    if (tid == 0) rowstart[N] = wo[4];
}

__global__ __launch_bounds__(256) void scanC(int* __restrict__ cnt,
                                             const int* __restrict__ boff,
                                             int* __restrict__ rowstart,
                                             float* __restrict__ dinv, int N) {
    __shared__ int wt[4];
    __shared__ int wo[4];
    int tid = threadIdx.x, lane = tid & 63, w = tid >> 6;
    int i = blockIdx.x * 256 + tid;
    int v = (i < N) ? cnt[i] : 0;
    int s = v;
#pragma unroll
    for (int off = 1; off < 64; off <<= 1) {
        int t = __shfl_up(s, off);
        if (lane >= off) s += t;
    }
    if (lane == 63) wt[w] = s;
    __syncthreads();
    if (tid == 0) {
        int run = 0;
#pragma unroll
        for (int k = 0; k < 4; ++k) { wo[k] = run; run += wt[k]; }
    }
    __syncthreads();
    if (i < N) {
        int excl = boff[blockIdx.x] + wo[w] + (s - v);
        rowstart[i] = excl;
        cnt[i] = excl;  // becomes cursor
        dinv[i] = rsqrtf(1.0f + (float)v);
    }
}

// ---- counting-sort fill ----------------------------------------------------
__global__ void fill_csr(const int* __restrict__ idx, const int* __restrict__ flag,
                         int* __restrict__ cursor, int* __restrict__ srcs, int E) {
    int e = blockIdx.x * blockDim.x + threadIdx.x;
    if (e >= E) return;
    int f = *flag;
    int src, dst;
    if (f) { src = idx[2 * e]; dst = idx[2 * (E + e)]; }
    else   { src = idx[e];     dst = idx[E + e]; }
    int pos = atomicAdd(&cursor[dst], 1);
    srcs[pos] = src;
}

// ---- GEMM: out_bf16[N,128] = A[N,128] @ W[128,128] -------------------------
// 128x128 tile, 256 threads, 8x8 split microtile. LDS 128 KB -> 1 block/CU.
template <int ABF>
__global__ __launch_bounds__(256) void gemm_t(const void* __restrict__ Ap,
                                              const float* __restrict__ W,
                                              unsigned short* __restrict__ outb,
                                              int N) {
    __shared__ float Wl[128 * 128];
    __shared__ float Xt[128 * 128];  // Xt[k][r]
    int tid = threadIdx.x;
    int row0 = blockIdx.x * 128;

    const float4* W4 = (const float4*)W;
    float4* Wl4 = (float4*)Wl;
#pragma unroll
    for (int i = 0; i < 16; ++i) Wl4[tid + 256 * i] = W4[tid + 256 * i];

    {
        int r = tid >> 1, kh = tid & 1;
        int gr = row0 + r;
#pragma unroll
        for (int i = 0; i < 16; ++i) {
            int k = kh * 64 + i * 4;
            float f0, f1, f2, f3;
            if (gr < N) {
                if (ABF) {
                    // 4 bf16 per uint2 (8B); index = gr*32 + k/4
                    uint2 q = ((const uint2*)Ap)[(size_t)gr * 32 + (k >> 2)];
                    f0 = b2f(q.x & 0xFFFFu); f1 = b2f(q.x >> 16);
                    f2 = b2f(q.y & 0xFFFFu); f3 = b2f(q.y >> 16);
                } else {
                    float4 v = ((const float4*)Ap)[(size_t)gr * 32 + (k >> 2)];
                    f0 = v.x; f1 = v.y; f2 = v.z; f3 = v.w;
                }
            } else {
                f0 = f1 = f2 = f3 = 0.f;
            }
            Xt[(k + 0) * 128 + r] = f0;
            Xt[(k + 1) * 128 + r] = f1;
            Xt[(k + 2) * 128 + r] = f2;
            Xt[(k + 3) * 128 + r] = f3;
        }
    }
    __syncthreads();

    int cg = tid & 15;   // cols {4cg..4cg+3} u {64+4cg..64+4cg+3}
    int rg = tid >> 4;   // rows {4rg..4rg+3} u {64+4rg..64+4rg+3}
    float acc[8][8];
#pragma unroll
    for (int i = 0; i < 8; ++i)
#pragma unroll
        for (int j = 0; j < 8; ++j) acc[i][j] = 0.f;

    const float4* Xt4 = (const float4*)Xt;
#pragma unroll 2
    for (int k = 0; k < 128; ++k) {
        float4 wa = Wl4[k * 32 + cg];
        float4 wb = Wl4[k * 32 + 16 + cg];
        float4 xa = Xt4[k * 32 + rg];
        float4 xb = Xt4[k * 32 + 16 + rg];
        float xs[8] = {xa.x, xa.y, xa.z, xa.w, xb.x, xb.y, xb.z, xb.w};
        float ws[8] = {wa.x, wa.y, wa.z, wa.w, wb.x, wb.y, wb.z, wb.w};
#pragma unroll
        for (int i = 0; i < 8; ++i)
#pragma unroll
            for (int j = 0; j < 8; ++j) acc[i][j] += xs[i] * ws[j];
    }

    ushort4* out4 = (ushort4*)outb;
#pragma unroll
    for (int i = 0; i < 8; ++i) {
        int r = row0 + ((i < 4) ? (rg * 4 + i) : (64 + rg * 4 + (i - 4)));
        if (r < N) {
            ushort4 oa, ob;
            oa.x = f2b(acc[i][0]); oa.y = f2b(acc[i][1]);
            oa.z = f2b(acc[i][2]); oa.w = f2b(acc[i][3]);
            ob.x = f2b(acc[i][4]); ob.y = f2b(acc[i][5]);
            ob.z = f2b(acc[i][6]); ob.w = f2b(acc[i][7]);
            out4[(size_t)r * 32 + cg] = oa;
            out4[(size_t)r * 32 + 16 + cg] = ob;
        }
    }
}

// ---- aggregation: one wave/node, bf16 gather, 2 edges per iteration --------
__global__ __launch_bounds__(256) void agg_node(const unsigned short* __restrict__ hb,
                                                const int* __restrict__ rowstart,
                                                const int* __restrict__ srcs,
                                                const float* __restrict__ dinv,
                                                const float* __restrict__ b,
                                                unsigned short* __restrict__ outb,
                                                int N, int do_relu) {
    int w = threadIdx.x >> 6, lane = threadIdx.x & 63;
    int node = blockIdx.x * 4 + w;
    if (node >= N) return;
    int beg = rowstart[node], end = rowstart[node + 1];
    float dn = dinv[node];
    int half = lane >> 5;
    int q = lane & 31;
    const uint2* hb4 = (const uint2*)hb;  // 4 bf16 per uint2
    float a0 = 0.f, a1 = 0.f, a2 = 0.f, a3 = 0.f;

    for (int j0 = beg; j0 < end; j0 += 64) {
        int myj = j0 + lane;
        int ms = 0;
        float md = 0.f;
        if (myj < end) { ms = srcs[myj]; md = dinv[ms]; }
        int m = min(64, end - j0);
        for (int k = 0; k < m; k += 2) {
            int idx2 = k + half;            // may be ==m when m odd: md=0 there
            int s = __shfl(ms, idx2);
            float c = dn * __shfl(md, idx2);
            uint2 v = hb4[(size_t)s * 32 + q];
            a0 += c * b2f(v.x & 0xFFFFu);
            a1 += c * b2f(v.x >> 16);
            a2 += c * b2f(v.y & 0xFFFFu);
            a3 += c * b2f(v.y >> 16);
        }
    }
    a0 += __shfl_xor(a0, 32);
    a1 += __shfl_xor(a1, 32);
    a2 += __shfl_xor(a2, 32);
    a3 += __shfl_xor(a3, 32);

    if (half == 0) {
        uint2 sv = hb4[(size_t)node * 32 + q];
        float d2 = dn * dn;
        float4 bb = ((const float4*)b)[q];
        float r0 = a0 + d2 * b2f(sv.x & 0xFFFFu) + bb.x;
        float r1 = a1 + d2 * b2f(sv.x >> 16) + bb.y;
        float r2 = a2 + d2 * b2f(sv.y & 0xFFFFu) + bb.z;
        float r3 = a3 + d2 * b2f(sv.y >> 16) + bb.w;
        if (do_relu) {
            r0 = fmaxf(r0, 0.f); r1 = fmaxf(r1, 0.f);
            r2 = fmaxf(r2, 0.f); r3 = fmaxf(r3, 0.f);
        }
        ushort4 o;
        o.x = f2b(r0); o.y = f2b(r1); o.z = f2b(r2); o.w = f2b(r3);
        ((ushort4*)outb)[(size_t)node * 32 + q] = o;
    }
}

// ---- output: out[N,40] = log_softmax(h2 @ W_out + b_out) -------------------
// 128 rows x 40 cols per block. Thread (r4=tid>>3, cg=tid&7): 4 rows x 5 cols.
// Per k: 1 conflict-free ds_read_b128 (4 rows) + 5 scalar W reads -> 20 FMA.
// Softmax reduced across the 8 lanes sharing a row group via shfl_xor 1/2/4.
__global__ __launch_bounds__(256) void out_gemm(const unsigned short* __restrict__ h2b,
                                                const float* __restrict__ Wout,
                                                const float* __restrict__ bout,
                                                float* __restrict__ out, int N) {
    __shared__ float Xt[128 * 128];  // Xt[k][r], f32
    __shared__ float Wl[128 * 40];
    __shared__ float bl[40];
    int tid = threadIdx.x;
    int row0 = blockIdx.x * 128;

    for (int i = tid; i < 128 * 40; i += 256) Wl[i] = Wout[i];
    if (tid < 40) bl[tid] = bout[tid];

    {
        int r = tid >> 1, kh = tid & 1;
        int gr = row0 + r;
#pragma unroll
        for (int i = 0; i < 16; ++i) {
            int k = kh * 64 + i * 4;
            float f0, f1, f2, f3;
            if (gr < N) {
                uint2 q = ((const uint2*)h2b)[(size_t)gr * 32 + (k >> 2)];
                f0 = b2f(q.x & 0xFFFFu); f1 = b2f(q.x >> 16);
                f2 = b2f(q.y & 0xFFFFu); f3 = b2f(q.y >> 16);
            } else {
                f0 = f1 = f2 = f3 = 0.f;
            }
            Xt[(k + 0) * 128 + r] = f0;
            Xt[(k + 1) * 128 + r] = f1;
            Xt[(k + 2) * 128 + r] = f2;
            Xt[(k + 3) * 128 + r] = f3;
        }
    }
    __syncthreads();

    int cg = tid & 7;    // cols 5cg..5cg+4
    int r4 = tid >> 3;   // rows r4*4..r4*4+3
    float bias[5];
#pragma unroll
    for (int c = 0; c < 5; ++c) bias[c] = bl[5 * cg + c];

    float acc[4][5];
#pragma unroll
    for (int j = 0; j < 4; ++j)
#pragma unroll
        for (int c = 0; c < 5; ++c) acc[j][c] = 0.f;

    const float4* Xt4 = (const float4*)Xt;
#pragma unroll 4
    for (int k = 0; k < 128; ++k) {
        float4 xv = Xt4[k * 32 + r4];
        const float* wr = &Wl[k * 40 + 5 * cg];
        float w0 = wr[0], w1 = wr[1], w2 = wr[2], w3 = wr[3], w4 = wr[4];
        float xs[4] = {xv.x, xv.y, xv.z, xv.w};
#pragma unroll
        for (int j = 0; j < 4; ++j) {
            acc[j][0] += xs[j] * w0;
            acc[j][1] += xs[j] * w1;
            acc[j][2] += xs[j] * w2;
            acc[j][3] += xs[j] * w3;
            acc[j][4] += xs[j] * w4;
        }
    }

#pragma unroll
    for (int j = 0; j < 4; ++j) {
        int r = row0 + r4 * 4 + j;
        if (r >= N) continue;   // uniform across the 8-lane shfl group (same r4)
        float v[5];
        float m = -INFINITY;
#pragma unroll
        for (int c = 0; c < 5; ++c) { v[c] = acc[j][c] + bias[c]; m = fmaxf(m, v[c]); }
        m = fmaxf(m, __shfl_xor(m, 1));
        m = fmaxf(m, __shfl_xor(m, 2));
        m = fmaxf(m, __shfl_xor(m, 4));
        float s = 0.f;
#pragma unroll
        for (int c = 0; c < 5; ++c) s += expf(v[c] - m);
        s += __shfl_xor(s, 1);
        s += __shfl_xor(s, 2);
        s += __shfl_xor(s, 4);
        float ls = logf(s);
#pragma unroll
        for (int c = 0; c < 5; ++c) out[(size_t)r * 40 + 5 * cg + c] = v[c] - m - ls;
    }
}

static inline size_t al256(size_t x) { return (x + 255) & ~(size_t)255; }

extern "C" void kernel_launch(void* const* d_in, const int* in_sizes, int n_in,
                              void* d_out, int out_size, void* d_ws, size_t ws_size,
                              hipStream_t stream) {
    const float* x     = (const float*)d_in[0];
    const int*   idx   = (const int*)d_in[1];
    const float* W_in  = (const float*)d_in[2];
    const float* b_in  = (const float*)d_in[3];
    const float* W1    = (const float*)d_in[4];
    const float* b1    = (const float*)d_in[5];
    const float* W_out = (const float*)d_in[6];
    const float* b_out = (const float*)d_in[7];
    float* out = (float*)d_out;

    int N = in_sizes[0] / 128;
    int E = in_sizes[1] / 2;

    char* ws = (char*)d_ws;
    size_t off = 0;
    int* flag = (int*)(ws + off);       off += 256;
    int* cnt = (int*)(ws + off);        off += al256((size_t)N * 4);
    int* rowstart = (int*)(ws + off);   off += al256((size_t)(N + 1) * 4);
    float* dinv = (float*)(ws + off);   off += al256((size_t)N * 4);
    int* srcs = (int*)(ws + off);       off += al256((size_t)E * 4);
    int* bsum = (int*)(ws + off);       off += 2048;
    int* boff = (int*)(ws + off);       off += 2048;
    unsigned short* B0 = (unsigned short*)(ws + off);  off += (size_t)N * 128 * 2;
    unsigned short* B1 = (unsigned short*)(ws + off);

    int nb_e = (E + THREADS - 1) / THREADS;
    int nb_n = (N + THREADS - 1) / THREADS;
    int nb_g = (N + 127) / 128;
    int nb_a = (N + 3) / 4;

    detect_idx64<<<1, 64, 0, stream>>>(idx, flag);
    hipMemsetAsync(cnt, 0, (size_t)N * 4, stream);
    hist_dst<<<nb_e, THREADS, 0, stream>>>(idx, flag, cnt, E);
    scanA<<<nb_n, THREADS, 0, stream>>>(cnt, bsum, N);
    scanB<<<1, THREADS, 0, stream>>>(bsum, boff, rowstart, nb_n, N);
    scanC<<<nb_n, THREADS, 0, stream>>>(cnt, boff, rowstart, dinv, N);
    fill_csr<<<nb_e, THREADS, 0, stream>>>(idx, flag, cnt, srcs, E);

    // layer 1
    gemm_t<0><<<nb_g, THREADS, 0, stream>>>(x, W_in, B0, N);                  // h0
    agg_node<<<nb_a, THREADS, 0, stream>>>(B0, rowstart, srcs, dinv, b_in,
                                           B1, N, 0);                         // h1
    // layer 2
    gemm_t<1><<<nb_g, THREADS, 0, stream>>>(B1, W1, B0, N);                   // t
    agg_node<<<nb_a, THREADS, 0, stream>>>(B0, rowstart, srcs, dinv, b1,
                                           B1, N, 1);                         // h2
    // output layer + fused log_softmax
    out_gemm<<<nb_g, THREADS, 0, stream>>>(B1, W_out, b_out, out, N);
}

// Round 6
// 306.896 us; speedup vs baseline: 9.8714x; 1.1918x over previous
//
#include <hip/hip_runtime.h>
#include <math.h>

// GCN 3-layer forward, round 6:
//  - CSR build: fill_pos (atomic, coalesced packed rec) + scan + fill_place
//    (no atomic, ushort scatter). hist_dst eliminated.
//  - agg_node: uint4 gathers, 4 edges per wave-iteration, ushort srcs.
//  - gemm_t: 64x128 tile, W bf16 in LDS (64KB total -> 2 blocks/CU).
// Dataflow (B0/B1 bf16 [N,128]):
//  gemm1: x(f32) @ W_in -> B0 ; agg1 -> B1 ; gemm2: B1 @ W1 -> B0 ;
//  agg2(relu) -> B1 ; out_gemm: log_softmax(B1 @ W_out + b_out) -> d_out.
// NOTE: assumes N < 65536 (src/pos packed in 16 bits each).

#define THREADS 256

__device__ __forceinline__ float b2f(unsigned int lo16) {
    return __uint_as_float(lo16 << 16);
}
__device__ __forceinline__ unsigned short f2b(float f) {
    unsigned int u = __float_as_uint(f);
    u += 0x7FFFu + ((u >> 16) & 1u);   // RNE
    return (unsigned short)(u >> 16);
}

// ---- index-dtype detection: int64 arrays have high words == 0 -------------
__global__ void detect_idx64(const int* __restrict__ idx, int* __restrict__ flag) {
    int t = threadIdx.x;  // 64 threads
    unsigned long long b = __ballot(idx[2 * t + 1] == 0);
    if (t == 0) *flag = (b == 0xFFFFFFFFFFFFFFFFull) ? 1 : 0;
}

// ---- pass 1: per-edge position within its dst bucket + counts --------------
// rec[e] = src<<16 | pos  (coalesced 4B store); cnt[dst] ends as degree-1.
__global__ void fill_pos(const int* __restrict__ idx, const int* __restrict__ flag,
                         int* __restrict__ cnt, unsigned int* __restrict__ rec, int E) {
    int e = blockIdx.x * blockDim.x + threadIdx.x;
    if (e >= E) return;
    int f = *flag;
    int src, dst;
    if (f) { src = idx[2 * e]; dst = idx[2 * (E + e)]; }
    else   { src = idx[e];     dst = idx[E + e]; }
    unsigned int pos = (unsigned int)atomicAdd(&cnt[dst], 1);
    rec[e] = ((unsigned int)src << 16) | (pos & 0xFFFFu);
}

// ---- parallel scan (3 kernels) --------------------------------------------
__global__ __launch_bounds__(256) void scanA(const int* __restrict__ cnt,
                                             int* __restrict__ bsum, int N) {
    __shared__ int wt[4];
    int tid = threadIdx.x, lane = tid & 63, w = tid >> 6;
    int i = blockIdx.x * 256 + tid;
    int v = (i < N) ? cnt[i] : 0;
    int s = v;
#pragma unroll
    for (int off = 1; off < 64; off <<= 1) {
        int t = __shfl_up(s, off);
        if (lane >= off) s += t;
    }
    if (lane == 63) wt[w] = s;
    __syncthreads();
    if (tid == 0) bsum[blockIdx.x] = wt[0] + wt[1] + wt[2] + wt[3];
}

__global__ __launch_bounds__(256) void scanB(int* __restrict__ bsum,
                                             int* __restrict__ boff,
                                             int* __restrict__ rowstart,
                                             int nb, int N) {
    __shared__ int wt[4];
    __shared__ int wo[5];
    int tid = threadIdx.x, lane = tid & 63, w = tid >> 6;
    int v = (tid < nb) ? bsum[tid] : 0;
    int s = v;
#pragma unroll
    for (int off = 1; off < 64; off <<= 1) {
        int t = __shfl_up(s, off);
        if (lane >= off) s += t;
    }
    if (lane == 63) wt[w] = s;
    __syncthreads();
    if (tid == 0) {
        int run = 0;
#pragma unroll
        for (int k = 0; k < 4; ++k) { wo[k] = run; run += wt[k]; }
        wo[4] = run;
    }
    __syncthreads();
    if (tid < nb) boff[tid] = wo[w] + s - v;
    if (tid == 0) rowstart[N] = wo[4];
}

__global__ __launch_bounds__(256) void scanC(const int* __restrict__ cnt,
                                             const int* __restrict__ boff,
                                             int* __restrict__ rowstart,
                                             float* __restrict__ dinv, int N) {
    __shared__ int wt[4];
    __shared__ int wo[4];
    int tid = threadIdx.x, lane = tid & 63, w = tid >> 6;
    int i = blockIdx.x * 256 + tid;
    int v = (i < N) ? cnt[i] : 0;
    int s = v;
#pragma unroll
    for (int off = 1; off < 64; off <<= 1) {
        int t = __shfl_up(s, off);
        if (lane >= off) s += t;
    }
    if (lane == 63) wt[w] = s;
    __syncthreads();
    if (tid == 0) {
        int run = 0;
#pragma unroll
        for (int k = 0; k < 4; ++k) { wo[k] = run; run += wt[k]; }
    }
    __syncthreads();
    if (i < N) {
        rowstart[i] = boff[blockIdx.x] + wo[w] + (s - v);
        dinv[i] = rsqrtf(1.0f + (float)v);
    }
}

// ---- pass 2: place src (ushort) at rowstart[dst]+pos, no atomics -----------
__global__ void fill_place(const int* __restrict__ idx, const int* __restrict__ flag,
                           const unsigned int* __restrict__ rec,
                           const int* __restrict__ rowstart,
                           unsigned short* __restrict__ srcs, int E) {
    int e = blockIdx.x * blockDim.x + threadIdx.x;
    if (e >= E) return;
    int f = *flag;
    int dst = f ? idx[2 * (E + e)] : idx[E + e];
    unsigned int r = rec[e];
    srcs[rowstart[dst] + (int)(r & 0xFFFFu)] = (unsigned short)(r >> 16);
}

// ---- GEMM: out_bf16[N,128] = A[N,128] @ W[128,128] -------------------------
// 64x128 tile, 256 threads, microtile 4 rows x 8 cols (split 4+4).
// LDS: Xt f32 [128k][64r] 32KB + W bf16 [128k][128n] 32KB -> 2 blocks/CU.
template <int ABF>
__global__ __launch_bounds__(256) void gemm_t(const void* __restrict__ Ap,
                                              const float* __restrict__ W,
                                              unsigned short* __restrict__ outb,
                                              int N) {
    __shared__ float Xt[128 * 64];            // Xt[k][r]
    __shared__ unsigned short Wl[128 * 128];  // Wl[k][n] bf16
    int tid = threadIdx.x;
    int row0 = blockIdx.x * 64;

    // stage W -> bf16 (coalesced)
    const float4* W4 = (const float4*)W;
    ushort4* Wl4 = (ushort4*)Wl;
#pragma unroll
    for (int it = 0; it < 16; ++it) {
        int i = tid + 256 * it;       // i < 4096 covers 128x32 float4s
        float4 v = W4[i];
        ushort4 o;
        o.x = f2b(v.x); o.y = f2b(v.y); o.z = f2b(v.z); o.w = f2b(v.w);
        Wl4[i] = o;                   // ushorts [4i..4i+3] = Wl[k=i>>5][n=4*(i&31)..]
    }

    // stage X transposed f32
    {
        int r = tid >> 2, kq = tid & 3;
        int gr = row0 + r;
#pragma unroll
        for (int i = 0; i < 8; ++i) {
            int k = kq * 32 + i * 4;
            float f0, f1, f2, f3;
            if (gr < N) {
                if (ABF) {
                    uint2 qv = ((const uint2*)Ap)[(size_t)gr * 32 + (k >> 2)];
                    f0 = b2f(qv.x & 0xFFFFu); f1 = b2f(qv.x >> 16);
                    f2 = b2f(qv.y & 0xFFFFu); f3 = b2f(qv.y >> 16);
                } else {
                    float4 v = ((const float4*)Ap)[(size_t)gr * 32 + (k >> 2)];
                    f0 = v.x; f1 = v.y; f2 = v.z; f3 = v.w;
                }
            } else {
                f0 = f1 = f2 = f3 = 0.f;
            }
            Xt[(k + 0) * 64 + r] = f0;
            Xt[(k + 1) * 64 + r] = f1;
            Xt[(k + 2) * 64 + r] = f2;
            Xt[(k + 3) * 64 + r] = f3;
        }
    }
    __syncthreads();

    int cg = tid & 15;   // cols {4cg..4cg+3} u {64+4cg..64+4cg+3}
    int rg = tid >> 4;   // rows rg*4..rg*4+3
    float acc[4][8];
#pragma unroll
    for (int j = 0; j < 4; ++j)
#pragma unroll
        for (int c = 0; c < 8; ++c) acc[j][c] = 0.f;

    const float4* Xt4 = (const float4*)Xt;
    const uint2* Wlu = (const uint2*)Wl;    // 4 bf16 per uint2
#pragma unroll 4
    for (int k = 0; k < 128; ++k) {
        float4 xv = Xt4[k * 16 + rg];
        uint2 wa = Wlu[k * 32 + cg];
        uint2 wb = Wlu[k * 32 + 16 + cg];
        float ws[8];
        ws[0] = b2f(wa.x & 0xFFFFu); ws[1] = b2f(wa.x >> 16);
        ws[2] = b2f(wa.y & 0xFFFFu); ws[3] = b2f(wa.y >> 16);
        ws[4] = b2f(wb.x & 0xFFFFu); ws[5] = b2f(wb.x >> 16);
        ws[6] = b2f(wb.y & 0xFFFFu); ws[7] = b2f(wb.y >> 16);
        float xs[4] = {xv.x, xv.y, xv.z, xv.w};
#pragma unroll
        for (int j = 0; j < 4; ++j)
#pragma unroll
            for (int c = 0; c < 8; ++c) acc[j][c] += xs[j] * ws[c];
    }

    ushort4* out4 = (ushort4*)outb;
#pragma unroll
    for (int j = 0; j < 4; ++j) {
        int r = row0 + rg * 4 + j;
        if (r < N) {
            ushort4 oa, ob;
            oa.x = f2b(acc[j][0]); oa.y = f2b(acc[j][1]);
            oa.z = f2b(acc[j][2]); oa.w = f2b(acc[j][3]);
            ob.x = f2b(acc[j][4]); ob.y = f2b(acc[j][5]);
            ob.z = f2b(acc[j][6]); ob.w = f2b(acc[j][7]);
            out4[(size_t)r * 32 + cg] = oa;
            out4[(size_t)r * 32 + 16 + cg] = ob;
        }
    }
}

// ---- aggregation: one wave/node, uint4 gathers, 4 edges per iteration ------
// 16 lanes per edge (quarter = lane>>4), each lane 16B = 8 features.
__global__ __launch_bounds__(256) void agg_node(const unsigned short* __restrict__ hb,
                                                const int* __restrict__ rowstart,
                                                const unsigned short* __restrict__ srcs,
                                                const float* __restrict__ dinv,
                                                const float* __restrict__ b,
                                                unsigned short* __restrict__ outb,
                                                int N, int do_relu) {
    int w = threadIdx.x >> 6, lane = threadIdx.x & 63;
    int node = blockIdx.x * 4 + w;
    if (node >= N) return;
    int beg = rowstart[node], end = rowstart[node + 1];
    float dn = dinv[node];
    int quarter = lane >> 4, q = lane & 15;
    const uint4* hb8 = (const uint4*)hb;   // 8 bf16 per uint4
    float a0 = 0.f, a1 = 0.f, a2 = 0.f, a3 = 0.f;
    float a4 = 0.f, a5 = 0.f, a6 = 0.f, a7 = 0.f;

    for (int j0 = beg; j0 < end; j0 += 64) {
        int myj = j0 + lane;
        int ms = 0;
        float md = 0.f;
        if (myj < end) { ms = (int)srcs[myj]; md = dinv[ms]; }
        int m = min(64, end - j0);
#pragma unroll 2
        for (int k = 0; k < m; k += 4) {
            int idx2 = k + quarter;     // >= m possible on ragged tail: md=0 there
            int s = __shfl(ms, idx2);
            float c = dn * __shfl(md, idx2);
            uint4 v = hb8[(size_t)s * 16 + q];
            a0 += c * b2f(v.x & 0xFFFFu);
            a1 += c * b2f(v.x >> 16);
            a2 += c * b2f(v.y & 0xFFFFu);
            a3 += c * b2f(v.y >> 16);
            a4 += c * b2f(v.z & 0xFFFFu);
            a5 += c * b2f(v.z >> 16);
            a6 += c * b2f(v.w & 0xFFFFu);
            a7 += c * b2f(v.w >> 16);
        }
    }
    // combine the 4 quarters
    a0 += __shfl_xor(a0, 32); a1 += __shfl_xor(a1, 32);
    a2 += __shfl_xor(a2, 32); a3 += __shfl_xor(a3, 32);
    a4 += __shfl_xor(a4, 32); a5 += __shfl_xor(a5, 32);
    a6 += __shfl_xor(a6, 32); a7 += __shfl_xor(a7, 32);
    a0 += __shfl_xor(a0, 16); a1 += __shfl_xor(a1, 16);
    a2 += __shfl_xor(a2, 16); a3 += __shfl_xor(a3, 16);
    a4 += __shfl_xor(a4, 16); a5 += __shfl_xor(a5, 16);
    a6 += __shfl_xor(a6, 16); a7 += __shfl_xor(a7, 16);

    if (quarter == 0) {
        uint4 sv = hb8[(size_t)node * 16 + q];
        float d2 = dn * dn;
        float4 b0 = ((const float4*)b)[2 * q];
        float4 b1 = ((const float4*)b)[2 * q + 1];
        float r0 = a0 + d2 * b2f(sv.x & 0xFFFFu) + b0.x;
        float r1 = a1 + d2 * b2f(sv.x >> 16)     + b0.y;
        float r2 = a2 + d2 * b2f(sv.y & 0xFFFFu) + b0.z;
        float r3 = a3 + d2 * b2f(sv.y >> 16)     + b0.w;
        float r4 = a4 + d2 * b2f(sv.z & 0xFFFFu) + b1.x;
        float r5 = a5 + d2 * b2f(sv.z >> 16)     + b1.y;
        float r6 = a6 + d2 * b2f(sv.w & 0xFFFFu) + b1.z;
        float r7 = a7 + d2 * b2f(sv.w >> 16)     + b1.w;
        if (do_relu) {
            r0 = fmaxf(r0, 0.f); r1 = fmaxf(r1, 0.f);
            r2 = fmaxf(r2, 0.f); r3 = fmaxf(r3, 0.f);
            r4 = fmaxf(r4, 0.f); r5 = fmaxf(r5, 0.f);
            r6 = fmaxf(r6, 0.f); r7 = fmaxf(r7, 0.f);
        }
        uint4 o;
        o.x = (unsigned int)f2b(r0) | ((unsigned int)f2b(r1) << 16);
        o.y = (unsigned int)f2b(r2) | ((unsigned int)f2b(r3) << 16);
        o.z = (unsigned int)f2b(r4) | ((unsigned int)f2b(r5) << 16);
        o.w = (unsigned int)f2b(r6) | ((unsigned int)f2b(r7) << 16);
        ((uint4*)outb)[(size_t)node * 16 + q] = o;
    }
}

// ---- output: out[N,40] = log_softmax(h2 @ W_out + b_out) -------------------
__global__ __launch_bounds__(256) void out_gemm(const unsigned short* __restrict__ h2b,
                                                const float* __restrict__ Wout,
                                                const float* __restrict__ bout,
                                                float* __restrict__ out, int N) {
    __shared__ float Xt[128 * 128];  // Xt[k][r], f32
    __shared__ float Wl[128 * 40];
    __shared__ float bl[40];
    int tid = threadIdx.x;
    int row0 = blockIdx.x * 128;

    for (int i = tid; i < 128 * 40; i += 256) Wl[i] = Wout[i];
    if (tid < 40) bl[tid] = bout[tid];

    {
        int r = tid >> 1, kh = tid & 1;
        int gr = row0 + r;
#pragma unroll
        for (int i = 0; i < 16; ++i) {
            int k = kh * 64 + i * 4;
            float f0, f1, f2, f3;
            if (gr < N) {
                uint2 qv = ((const uint2*)h2b)[(size_t)gr * 32 + (k >> 2)];
                f0 = b2f(qv.x & 0xFFFFu); f1 = b2f(qv.x >> 16);
                f2 = b2f(qv.y & 0xFFFFu); f3 = b2f(qv.y >> 16);
            } else {
                f0 = f1 = f2 = f3 = 0.f;
            }
            Xt[(k + 0) * 128 + r] = f0;
            Xt[(k + 1) * 128 + r] = f1;
            Xt[(k + 2) * 128 + r] = f2;
            Xt[(k + 3) * 128 + r] = f3;
        }
    }
    __syncthreads();

    int cg = tid & 7;    // cols 5cg..5cg+4
    int r4 = tid >> 3;   // rows r4*4..r4*4+3
    float bias[5];
#pragma unroll
    for (int c = 0; c < 5; ++c) bias[c] = bl[5 * cg + c];

    float acc[4][5];
#pragma unroll
    for (int j = 0; j < 4; ++j)
#pragma unroll
        for (int c = 0; c < 5; ++c) acc[j][c] = 0.f;

    const float4* Xt4 = (const float4*)Xt;
#pragma unroll 4
    for (int k = 0; k < 128; ++k) {
        float4 xv = Xt4[k * 32 + r4];
        const float* wr = &Wl[k * 40 + 5 * cg];
        float w0 = wr[0], w1 = wr[1], w2 = wr[2], w3 = wr[3], w4 = wr[4];
        float xs[4] = {xv.x, xv.y, xv.z, xv.w};
#pragma unroll
        for (int j = 0; j < 4; ++j) {
            acc[j][0] += xs[j] * w0;
            acc[j][1] += xs[j] * w1;
            acc[j][2] += xs[j] * w2;
            acc[j][3] += xs[j] * w3;
            acc[j][4] += xs[j] * w4;
        }
    }

#pragma unroll
    for (int j = 0; j < 4; ++j) {
        int r = row0 + r4 * 4 + j;
        if (r >= N) continue;   // uniform across the 8-lane shfl group (same r4)
        float v[5];
        float m = -INFINITY;
#pragma unroll
        for (int c = 0; c < 5; ++c) { v[c] = acc[j][c] + bias[c]; m = fmaxf(m, v[c]); }
        m = fmaxf(m, __shfl_xor(m, 1));
        m = fmaxf(m, __shfl_xor(m, 2));
        m = fmaxf(m, __shfl_xor(m, 4));
        float s = 0.f;
#pragma unroll
        for (int c = 0; c < 5; ++c) s += expf(v[c] - m);
        s += __shfl_xor(s, 1);
        s += __shfl_xor(s, 2);
        s += __shfl_xor(s, 4);
        float ls = logf(s);
#pragma unroll
        for (int c = 0; c < 5; ++c) out[(size_t)r * 40 + 5 * cg + c] = v[c] - m - ls;
    }
}

static inline size_t al256(size_t x) { return (x + 255) & ~(size_t)255; }

extern "C" void kernel_launch(void* const* d_in, const int* in_sizes, int n_in,
                              void* d_out, int out_size, void* d_ws, size_t ws_size,
                              hipStream_t stream) {
    const float* x     = (const float*)d_in[0];
    const int*   idx   = (const int*)d_in[1];
    const float* W_in  = (const float*)d_in[2];
    const float* b_in  = (const float*)d_in[3];
    const float* W1    = (const float*)d_in[4];
    const float* b1    = (const float*)d_in[5];
    const float* W_out = (const float*)d_in[6];
    const float* b_out = (const float*)d_in[7];
    float* out = (float*)d_out;

    int N = in_sizes[0] / 128;
    int E = in_sizes[1] / 2;

    char* ws = (char*)d_ws;
    size_t off = 0;
    int* flag = (int*)(ws + off);              off += 256;
    int* cnt = (int*)(ws + off);               off += al256((size_t)N * 4);
    int* rowstart = (int*)(ws + off);          off += al256((size_t)(N + 1) * 4);
    float* dinv = (float*)(ws + off);          off += al256((size_t)N * 4);
    unsigned short* srcs = (unsigned short*)(ws + off); off += al256((size_t)E * 2);
    unsigned int* rec = (unsigned int*)(ws + off);      off += al256((size_t)E * 4);
    int* bsum = (int*)(ws + off);              off += 2048;
    int* boff = (int*)(ws + off);              off += 2048;
    unsigned short* B0 = (unsigned short*)(ws + off);   off += (size_t)N * 128 * 2;
    unsigned short* B1 = (unsigned short*)(ws + off);

    int nb_e = (E + THREADS - 1) / THREADS;
    int nb_n = (N + THREADS - 1) / THREADS;   // scan blocks (<=256 for N<=65536)
    int nb_g = (N + 63) / 64;
    int nb_o = (N + 127) / 128;
    int nb_a = (N + 3) / 4;

    detect_idx64<<<1, 64, 0, stream>>>(idx, flag);
    hipMemsetAsync(cnt, 0, (size_t)N * 4, stream);
    fill_pos<<<nb_e, THREADS, 0, stream>>>(idx, flag, cnt, rec, E);
    scanA<<<nb_n, THREADS, 0, stream>>>(cnt, bsum, N);
    scanB<<<1, THREADS, 0, stream>>>(bsum, boff, rowstart, nb_n, N);
    scanC<<<nb_n, THREADS, 0, stream>>>(cnt, boff, rowstart, dinv, N);
    fill_place<<<nb_e, THREADS, 0, stream>>>(idx, flag, rec, rowstart, srcs, E);

    // layer 1
    gemm_t<0><<<nb_g, THREADS, 0, stream>>>(x, W_in, B0, N);                  // h0
    agg_node<<<nb_a, THREADS, 0, stream>>>(B0, rowstart, srcs, dinv, b_in,
                                           B1, N, 0);                         // h1
    // layer 2
    gemm_t<1><<<nb_g, THREADS, 0, stream>>>(B1, W1, B0, N);                   // t
    agg_node<<<nb_a, THREADS, 0, stream>>>(B0, rowstart, srcs, dinv, b1,
                                           B1, N, 1);                         // h2
    // output layer + fused log_softmax
    out_gemm<<<nb_o, THREADS, 0, stream>>>(B1, W_out, b_out, out, N);
}

// Round 7
// 263.440 us; speedup vs baseline: 11.4997x; 1.1650x over previous
//
#include <hip/hip_runtime.h>
#include <math.h>

// GCN 3-layer forward, round 7: MFMA (16x16x32 bf16) GEMMs.
//  - pack_w: W[128,128] f32 -> B-fragment-ordered bf16 (32KB), once per launch.
//  - gemm_mfma: 64 rows/block (4 waves x 16 rows), A-frags direct from global,
//    B-frags coalesced from packed W (L2-hot), LDS-bounce epilogue.
//  - CSR build / agg_node / out_gemm unchanged from round 6.
// Dataflow (B0/B1 bf16 [N,128]):
//  gemm1: x(f32) @ W_in -> B0 ; agg1 -> B1 ; gemm2: B1 @ W1 -> B0 ;
//  agg2(relu) -> B1 ; out_gemm: log_softmax(B1 @ W_out + b_out) -> d_out.
// NOTE: assumes N < 65536.

#define THREADS 256

typedef __attribute__((ext_vector_type(8))) short short8v;   // 8 bf16
typedef __attribute__((ext_vector_type(4))) float float4v;   // 4 f32 acc

__device__ __forceinline__ float b2f(unsigned int lo16) {
    return __uint_as_float(lo16 << 16);
}
__device__ __forceinline__ unsigned short f2b(float f) {
    unsigned int u = __float_as_uint(f);
    u += 0x7FFFu + ((u >> 16) & 1u);   // RNE
    return (unsigned short)(u >> 16);
}

// ---- index-dtype detection: int64 arrays have high words == 0 -------------
__global__ void detect_idx64(const int* __restrict__ idx, int* __restrict__ flag) {
    int t = threadIdx.x;  // 64 threads
    unsigned long long b = __ballot(idx[2 * t + 1] == 0);
    if (t == 0) *flag = (b == 0xFFFFFFFFFFFFFFFFull) ? 1 : 0;
}

// ---- pass 1: per-edge position within its dst bucket + counts --------------
__global__ void fill_pos(const int* __restrict__ idx, const int* __restrict__ flag,
                         int* __restrict__ cnt, unsigned int* __restrict__ rec, int E) {
    int e = blockIdx.x * blockDim.x + threadIdx.x;
    if (e >= E) return;
    int f = *flag;
    int src, dst;
    if (f) { src = idx[2 * e]; dst = idx[2 * (E + e)]; }
    else   { src = idx[e];     dst = idx[E + e]; }
    unsigned int pos = (unsigned int)atomicAdd(&cnt[dst], 1);
    rec[e] = ((unsigned int)src << 16) | (pos & 0xFFFFu);
}

// ---- parallel scan (3 kernels) --------------------------------------------
__global__ __launch_bounds__(256) void scanA(const int* __restrict__ cnt,
                                             int* __restrict__ bsum, int N) {
    __shared__ int wt[4];
    int tid = threadIdx.x, lane = tid & 63, w = tid >> 6;
    int i = blockIdx.x * 256 + tid;
    int v = (i < N) ? cnt[i] : 0;
    int s = v;
#pragma unroll
    for (int off = 1; off < 64; off <<= 1) {
        int t = __shfl_up(s, off);
        if (lane >= off) s += t;
    }
    if (lane == 63) wt[w] = s;
    __syncthreads();
    if (tid == 0) bsum[blockIdx.x] = wt[0] + wt[1] + wt[2] + wt[3];
}

__global__ __launch_bounds__(256) void scanB(int* __restrict__ bsum,
                                             int* __restrict__ boff,
                                             int* __restrict__ rowstart,
                                             int nb, int N) {
    __shared__ int wt[4];
    __shared__ int wo[5];
    int tid = threadIdx.x, lane = tid & 63, w = tid >> 6;
    int v = (tid < nb) ? bsum[tid] : 0;
    int s = v;
#pragma unroll
    for (int off = 1; off < 64; off <<= 1) {
        int t = __shfl_up(s, off);
        if (lane >= off) s += t;
    }
    if (lane == 63) wt[w] = s;
    __syncthreads();
    if (tid == 0) {
        int run = 0;
#pragma unroll
        for (int k = 0; k < 4; ++k) { wo[k] = run; run += wt[k]; }
        wo[4] = run;
    }
    __syncthreads();
    if (tid < nb) boff[tid] = wo[w] + s - v;
    if (tid == 0) rowstart[N] = wo[4];
}

__global__ __launch_bounds__(256) void scanC(const int* __restrict__ cnt,
                                             const int* __restrict__ boff,
                                             int* __restrict__ rowstart,
                                             float* __restrict__ dinv, int N) {
    __shared__ int wt[4];
    __shared__ int wo[4];
    int tid = threadIdx.x, lane = tid & 63, w = tid >> 6;
    int i = blockIdx.x * 256 + tid;
    int v = (i < N) ? cnt[i] : 0;
    int s = v;
#pragma unroll
    for (int off = 1; off < 64; off <<= 1) {
        int t = __shfl_up(s, off);
        if (lane >= off) s += t;
    }
    if (lane == 63) wt[w] = s;
    __syncthreads();
    if (tid == 0) {
        int run = 0;
#pragma unroll
        for (int k = 0; k < 4; ++k) { wo[k] = run; run += wt[k]; }
    }
    __syncthreads();
    if (i < N) {
        rowstart[i] = boff[blockIdx.x] + wo[w] + (s - v);
        dinv[i] = rsqrtf(1.0f + (float)v);
    }
}

// ---- pass 2: place src (ushort) at rowstart[dst]+pos, no atomics -----------
__global__ void fill_place(const int* __restrict__ idx, const int* __restrict__ flag,
                           const unsigned int* __restrict__ rec,
                           const int* __restrict__ rowstart,
                           unsigned short* __restrict__ srcs, int E) {
    int e = blockIdx.x * blockDim.x + threadIdx.x;
    if (e >= E) return;
    int f = *flag;
    int dst = f ? idx[2 * (E + e)] : idx[E + e];
    unsigned int r = rec[e];
    srcs[rowstart[dst] + (int)(r & 0xFFFFu)] = (unsigned short)(r >> 16);
}

// ---- pack W[128,128] f32 into B-fragment order (bf16) ----------------------
// slot s = (ct*4+kb)*64 + l ; lane l holds B[k=kb*32+(l>>4)*8 + e][col=ct*16+(l&15)]
__global__ __launch_bounds__(256) void pack_w(const float* __restrict__ W,
                                              uint4* __restrict__ wpk) {
    int tid = threadIdx.x;
    for (int it = 0; it < 8; ++it) {
        int s = it * 256 + tid;            // 2048 slots
        int ct = s >> 8;
        int kb = (s >> 6) & 3;
        int l  = s & 63;
        int col = ct * 16 + (l & 15);
        int k0  = kb * 32 + ((l >> 4) << 3);
        unsigned short e0 = f2b(W[(k0 + 0) * 128 + col]);
        unsigned short e1 = f2b(W[(k0 + 1) * 128 + col]);
        unsigned short e2 = f2b(W[(k0 + 2) * 128 + col]);
        unsigned short e3 = f2b(W[(k0 + 3) * 128 + col]);
        unsigned short e4 = f2b(W[(k0 + 4) * 128 + col]);
        unsigned short e5 = f2b(W[(k0 + 5) * 128 + col]);
        unsigned short e6 = f2b(W[(k0 + 6) * 128 + col]);
        unsigned short e7 = f2b(W[(k0 + 7) * 128 + col]);
        uint4 u;
        u.x = (unsigned int)e0 | ((unsigned int)e1 << 16);
        u.y = (unsigned int)e2 | ((unsigned int)e3 << 16);
        u.z = (unsigned int)e4 | ((unsigned int)e5 << 16);
        u.w = (unsigned int)e6 | ((unsigned int)e7 << 16);
        wpk[s] = u;
    }
}

// ---- MFMA GEMM: out_bf16[N,128] = A[N,128] @ W(packed) ---------------------
// 256 threads = 4 waves; wave w owns rows [blk*64 + 16w, +16).
// A-frag: lane l = A[row0 + (l&15)][kb*32 + (l>>4)*8 .. +7]  (16B global load)
// B-frag: wpk[(ct*4+kb)*64 + l]  (coalesced, L2-hot)
// D: lane l, reg r -> row (l>>4)*4+r, col ct*16 + (l&15)  -> LDS bounce -> store
template <int ABF>
__global__ __launch_bounds__(256) void gemm_mfma(const void* __restrict__ Ap,
                                                 const uint4* __restrict__ wpk,
                                                 unsigned short* __restrict__ outb,
                                                 int N) {
    __shared__ unsigned short ol[64 * 128];   // 16KB epilogue bounce
    int tid = threadIdx.x;
    int w = tid >> 6, l = tid & 63;
    int lr = l & 15, lq = l >> 4;
    int row0 = blockIdx.x * 64 + w * 16;
    int arow = row0 + lr;
    int arow_c = (arow < N) ? arow : (N > 0 ? N - 1 : 0);  // clamped A row: only pollutes D rows >= N

    float4v acc[8];
#pragma unroll
    for (int ct = 0; ct < 8; ++ct) acc[ct] = (float4v){0.f, 0.f, 0.f, 0.f};

#pragma unroll
    for (int kb = 0; kb < 4; ++kb) {
        short8v af;
        if (ABF) {
            uint4 v = *(const uint4*)((const unsigned short*)Ap + (size_t)arow_c * 128 + kb * 32 + lq * 8);
            union { uint4 u; short8v s; } cv; cv.u = v; af = cv.s;
        } else {
            const float* ap = (const float*)Ap + (size_t)arow_c * 128 + kb * 32 + lq * 8;
            float4 va = *(const float4*)ap;
            float4 vb = *(const float4*)(ap + 4);
            uint4 u;
            u.x = (unsigned int)f2b(va.x) | ((unsigned int)f2b(va.y) << 16);
            u.y = (unsigned int)f2b(va.z) | ((unsigned int)f2b(va.w) << 16);
            u.z = (unsigned int)f2b(vb.x) | ((unsigned int)f2b(vb.y) << 16);
            u.w = (unsigned int)f2b(vb.z) | ((unsigned int)f2b(vb.w) << 16);
            union { uint4 uu; short8v s; } cv; cv.uu = u; af = cv.s;
        }
#pragma unroll
        for (int ct = 0; ct < 8; ++ct) {
            uint4 bv = wpk[(ct * 4 + kb) * 64 + l];
            union { uint4 u; short8v s; } cv; cv.u = bv; short8v bf = cv.s;
            acc[ct] = __builtin_amdgcn_mfma_f32_16x16x32_bf16(af, bf, acc[ct], 0, 0, 0);
        }
    }

    // epilogue: D -> LDS (bf16, D-layout) -> coalesced global store
#pragma unroll
    for (int ct = 0; ct < 8; ++ct) {
#pragma unroll
        for (int r = 0; r < 4; ++r) {
            int dr = lq * 4 + r;
            ol[(w * 16 + dr) * 128 + ct * 16 + lr] = f2b(acc[ct][r]);
        }
    }
    __syncthreads();
#pragma unroll
    for (int it = 0; it < 4; ++it) {
        int o = it * 4096 + tid * 16;        // byte offset into ol
        int rr = o >> 8;                      // local row (256B per row)
        int cb = o & 255;
        int gr = blockIdx.x * 64 + rr;
        if (gr < N) {
            uint4 v = *(const uint4*)((const char*)ol + o);
            *(uint4*)((char*)outb + (size_t)gr * 256 + cb) = v;
        }
    }
}

// ---- aggregation: one wave/node, uint4 gathers, 4 edges per iteration ------
__global__ __launch_bounds__(256) void agg_node(const unsigned short* __restrict__ hb,
                                                const int* __restrict__ rowstart,
                                                const unsigned short* __restrict__ srcs,
                                                const float* __restrict__ dinv,
                                                const float* __restrict__ b,
                                                unsigned short* __restrict__ outb,
                                                int N, int do_relu) {
    int w = threadIdx.x >> 6, lane = threadIdx.x & 63;
    int node = blockIdx.x * 4 + w;
    if (node >= N) return;
    int beg = rowstart[node], end = rowstart[node + 1];
    float dn = dinv[node];
    int quarter = lane >> 4, q = lane & 15;
    const uint4* hb8 = (const uint4*)hb;   // 8 bf16 per uint4
    float a0 = 0.f, a1 = 0.f, a2 = 0.f, a3 = 0.f;
    float a4 = 0.f, a5 = 0.f, a6 = 0.f, a7 = 0.f;

    for (int j0 = beg; j0 < end; j0 += 64) {
        int myj = j0 + lane;
        int ms = 0;
        float md = 0.f;
        if (myj < end) { ms = (int)srcs[myj]; md = dinv[ms]; }
        int m = min(64, end - j0);
#pragma unroll 2
        for (int k = 0; k < m; k += 4) {
            int idx2 = k + quarter;     // >= m possible on ragged tail: md=0 there
            int s = __shfl(ms, idx2);
            float c = dn * __shfl(md, idx2);
            uint4 v = hb8[(size_t)s * 16 + q];
            a0 += c * b2f(v.x & 0xFFFFu);
            a1 += c * b2f(v.x >> 16);
            a2 += c * b2f(v.y & 0xFFFFu);
            a3 += c * b2f(v.y >> 16);
            a4 += c * b2f(v.z & 0xFFFFu);
            a5 += c * b2f(v.z >> 16);
            a6 += c * b2f(v.w & 0xFFFFu);
            a7 += c * b2f(v.w >> 16);
        }
    }
    a0 += __shfl_xor(a0, 32); a1 += __shfl_xor(a1, 32);
    a2 += __shfl_xor(a2, 32); a3 += __shfl_xor(a3, 32);
    a4 += __shfl_xor(a4, 32); a5 += __shfl_xor(a5, 32);
    a6 += __shfl_xor(a6, 32); a7 += __shfl_xor(a7, 32);
    a0 += __shfl_xor(a0, 16); a1 += __shfl_xor(a1, 16);
    a2 += __shfl_xor(a2, 16); a3 += __shfl_xor(a3, 16);
    a4 += __shfl_xor(a4, 16); a5 += __shfl_xor(a5, 16);
    a6 += __shfl_xor(a6, 16); a7 += __shfl_xor(a7, 16);

    if (quarter == 0) {
        uint4 sv = hb8[(size_t)node * 16 + q];
        float d2 = dn * dn;
        float4 b0 = ((const float4*)b)[2 * q];
        float4 b1 = ((const float4*)b)[2 * q + 1];
        float r0 = a0 + d2 * b2f(sv.x & 0xFFFFu) + b0.x;
        float r1 = a1 + d2 * b2f(sv.x >> 16)     + b0.y;
        float r2 = a2 + d2 * b2f(sv.y & 0xFFFFu) + b0.z;
        float r3 = a3 + d2 * b2f(sv.y >> 16)     + b0.w;
        float r4 = a4 + d2 * b2f(sv.z & 0xFFFFu) + b1.x;
        float r5 = a5 + d2 * b2f(sv.z >> 16)     + b1.y;
        float r6 = a6 + d2 * b2f(sv.w & 0xFFFFu) + b1.z;
        float r7 = a7 + d2 * b2f(sv.w >> 16)     + b1.w;
        if (do_relu) {
            r0 = fmaxf(r0, 0.f); r1 = fmaxf(r1, 0.f);
            r2 = fmaxf(r2, 0.f); r3 = fmaxf(r3, 0.f);
            r4 = fmaxf(r4, 0.f); r5 = fmaxf(r5, 0.f);
            r6 = fmaxf(r6, 0.f); r7 = fmaxf(r7, 0.f);
        }
        uint4 o;
        o.x = (unsigned int)f2b(r0) | ((unsigned int)f2b(r1) << 16);
        o.y = (unsigned int)f2b(r2) | ((unsigned int)f2b(r3) << 16);
        o.z = (unsigned int)f2b(r4) | ((unsigned int)f2b(r5) << 16);
        o.w = (unsigned int)f2b(r6) | ((unsigned int)f2b(r7) << 16);
        ((uint4*)outb)[(size_t)node * 16 + q] = o;
    }
}

// ---- output: out[N,40] = log_softmax(h2 @ W_out + b_out) -------------------
__global__ __launch_bounds__(256) void out_gemm(const unsigned short* __restrict__ h2b,
                                                const float* __restrict__ Wout,
                                                const float* __restrict__ bout,
                                                float* __restrict__ out, int N) {
    __shared__ float Xt[128 * 128];  // Xt[k][r], f32
    __shared__ float Wl[128 * 40];
    __shared__ float bl[40];
    int tid = threadIdx.x;
    int row0 = blockIdx.x * 128;

    for (int i = tid; i < 128 * 40; i += 256) Wl[i] = Wout[i];
    if (tid < 40) bl[tid] = bout[tid];

    {
        int r = tid >> 1, kh = tid & 1;
        int gr = row0 + r;
#pragma unroll
        for (int i = 0; i < 16; ++i) {
            int k = kh * 64 + i * 4;
            float f0, f1, f2, f3;
            if (gr < N) {
                uint2 qv = ((const uint2*)h2b)[(size_t)gr * 32 + (k >> 2)];
                f0 = b2f(qv.x & 0xFFFFu); f1 = b2f(qv.x >> 16);
                f2 = b2f(qv.y & 0xFFFFu); f3 = b2f(qv.y >> 16);
            } else {
                f0 = f1 = f2 = f3 = 0.f;
            }
            Xt[(k + 0) * 128 + r] = f0;
            Xt[(k + 1) * 128 + r] = f1;
            Xt[(k + 2) * 128 + r] = f2;
            Xt[(k + 3) * 128 + r] = f3;
        }
    }
    __syncthreads();

    int cg = tid & 7;    // cols 5cg..5cg+4
    int r4 = tid >> 3;   // rows r4*4..r4*4+3
    float bias[5];
#pragma unroll
    for (int c = 0; c < 5; ++c) bias[c] = bl[5 * cg + c];

    float acc[4][5];
#pragma unroll
    for (int j = 0; j < 4; ++j)
#pragma unroll
        for (int c = 0; c < 5; ++c) acc[j][c] = 0.f;

    const float4* Xt4 = (const float4*)Xt;
#pragma unroll 4
    for (int k = 0; k < 128; ++k) {
        float4 xv = Xt4[k * 32 + r4];
        const float* wr = &Wl[k * 40 + 5 * cg];
        float w0 = wr[0], w1 = wr[1], w2 = wr[2], w3 = wr[3], w4 = wr[4];
        float xs[4] = {xv.x, xv.y, xv.z, xv.w};
#pragma unroll
        for (int j = 0; j < 4; ++j) {
            acc[j][0] += xs[j] * w0;
            acc[j][1] += xs[j] * w1;
            acc[j][2] += xs[j] * w2;
            acc[j][3] += xs[j] * w3;
            acc[j][4] += xs[j] * w4;
        }
    }

#pragma unroll
    for (int j = 0; j < 4; ++j) {
        int r = row0 + r4 * 4 + j;
        if (r >= N) continue;   // uniform across the 8-lane shfl group (same r4)
        float v[5];
        float m = -INFINITY;
#pragma unroll
        for (int c = 0; c < 5; ++c) { v[c] = acc[j][c] + bias[c]; m = fmaxf(m, v[c]); }
        m = fmaxf(m, __shfl_xor(m, 1));
        m = fmaxf(m, __shfl_xor(m, 2));
        m = fmaxf(m, __shfl_xor(m, 4));
        float s = 0.f;
#pragma unroll
        for (int c = 0; c < 5; ++c) s += expf(v[c] - m);
        s += __shfl_xor(s, 1);
        s += __shfl_xor(s, 2);
        s += __shfl_xor(s, 4);
        float ls = logf(s);
#pragma unroll
        for (int c = 0; c < 5; ++c) out[(size_t)r * 40 + 5 * cg + c] = v[c] - m - ls;
    }
}

static inline size_t al256(size_t x) { return (x + 255) & ~(size_t)255; }

extern "C" void kernel_launch(void* const* d_in, const int* in_sizes, int n_in,
                              void* d_out, int out_size, void* d_ws, size_t ws_size,
                              hipStream_t stream) {
    const float* x     = (const float*)d_in[0];
    const int*   idx   = (const int*)d_in[1];
    const float* W_in  = (const float*)d_in[2];
    const float* b_in  = (const float*)d_in[3];
    const float* W1    = (const float*)d_in[4];
    const float* b1    = (const float*)d_in[5];
    const float* W_out = (const float*)d_in[6];
    const float* b_out = (const float*)d_in[7];
    float* out = (float*)d_out;

    int N = in_sizes[0] / 128;
    int E = in_sizes[1] / 2;

    char* ws = (char*)d_ws;
    size_t off = 0;
    int* flag = (int*)(ws + off);              off += 256;
    int* cnt = (int*)(ws + off);               off += al256((size_t)N * 4);
    int* rowstart = (int*)(ws + off);          off += al256((size_t)(N + 1) * 4);
    float* dinv = (float*)(ws + off);          off += al256((size_t)N * 4);
    unsigned short* srcs = (unsigned short*)(ws + off); off += al256((size_t)E * 2);
    unsigned int* rec = (unsigned int*)(ws + off);      off += al256((size_t)E * 4);
    int* bsum = (int*)(ws + off);              off += 2048;
    int* boff = (int*)(ws + off);              off += 2048;
    uint4* wpk1 = (uint4*)(ws + off);          off += 32768;   // packed W_in
    uint4* wpk2 = (uint4*)(ws + off);          off += 32768;   // packed W1
    unsigned short* B0 = (unsigned short*)(ws + off);   off += (size_t)N * 128 * 2;
    unsigned short* B1 = (unsigned short*)(ws + off);

    int nb_e = (E + THREADS - 1) / THREADS;
    int nb_n = (N + THREADS - 1) / THREADS;   // scan blocks (<=256 for N<=65536)
    int nb_g = (N + 63) / 64;
    int nb_o = (N + 127) / 128;
    int nb_a = (N + 3) / 4;

    detect_idx64<<<1, 64, 0, stream>>>(idx, flag);
    hipMemsetAsync(cnt, 0, (size_t)N * 4, stream);
    pack_w<<<1, THREADS, 0, stream>>>(W_in, wpk1);
    pack_w<<<1, THREADS, 0, stream>>>(W1, wpk2);
    fill_pos<<<nb_e, THREADS, 0, stream>>>(idx, flag, cnt, rec, E);
    scanA<<<nb_n, THREADS, 0, stream>>>(cnt, bsum, N);
    scanB<<<1, THREADS, 0, stream>>>(bsum, boff, rowstart, nb_n, N);
    scanC<<<nb_n, THREADS, 0, stream>>>(cnt, boff, rowstart, dinv, N);
    fill_place<<<nb_e, THREADS, 0, stream>>>(idx, flag, rec, rowstart, srcs, E);

    // layer 1
    gemm_mfma<0><<<nb_g, THREADS, 0, stream>>>(x, wpk1, B0, N);               // h0
    agg_node<<<nb_a, THREADS, 0, stream>>>(B0, rowstart, srcs, dinv, b_in,
                                           B1, N, 0);                         // h1
    // layer 2
    gemm_mfma<1><<<nb_g, THREADS, 0, stream>>>(B1, wpk2, B0, N);              // t
    agg_node<<<nb_a, THREADS, 0, stream>>>(B0, rowstart, srcs, dinv, b1,
                                           B1, N, 1);                         // h2
    // output layer + fused log_softmax
    out_gemm<<<nb_o, THREADS, 0, stream>>>(B1, W_out, b_out, out, N);
}

// Round 8
// 260.621 us; speedup vs baseline: 11.6241x; 1.0108x over previous
//
#include <hip/hip_runtime.h>
#include <math.h>

// GCN 3-layer forward, round 8:
//  - gemm_mfma: 128 rows/block (each wave: two 16-row tiles, B-frag reuse).
//  - agg_node: 8 edges in flight per inner iteration (2 independent gathers).
//  - pack_w: both weight matrices in one 2-block launch.
// Dataflow (B0/B1 bf16 [N,128]):
//  gemm1: x(f32) @ W_in -> B0 ; agg1 -> B1 ; gemm2: B1 @ W1 -> B0 ;
//  agg2(relu) -> B1 ; out_gemm: log_softmax(B1 @ W_out + b_out) -> d_out.
// NOTE: assumes N < 65536.

#define THREADS 256

typedef __attribute__((ext_vector_type(8))) short short8v;   // 8 bf16
typedef __attribute__((ext_vector_type(4))) float float4v;   // 4 f32 acc

__device__ __forceinline__ float b2f(unsigned int lo16) {
    return __uint_as_float(lo16 << 16);
}
__device__ __forceinline__ unsigned short f2b(float f) {
    unsigned int u = __float_as_uint(f);
    u += 0x7FFFu + ((u >> 16) & 1u);   // RNE
    return (unsigned short)(u >> 16);
}

// ---- index-dtype detection: int64 arrays have high words == 0 -------------
__global__ void detect_idx64(const int* __restrict__ idx, int* __restrict__ flag) {
    int t = threadIdx.x;  // 64 threads
    unsigned long long b = __ballot(idx[2 * t + 1] == 0);
    if (t == 0) *flag = (b == 0xFFFFFFFFFFFFFFFFull) ? 1 : 0;
}

// ---- pass 1: per-edge position within its dst bucket + counts --------------
__global__ void fill_pos(const int* __restrict__ idx, const int* __restrict__ flag,
                         int* __restrict__ cnt, unsigned int* __restrict__ rec, int E) {
    int e = blockIdx.x * blockDim.x + threadIdx.x;
    if (e >= E) return;
    int f = *flag;
    int src, dst;
    if (f) { src = idx[2 * e]; dst = idx[2 * (E + e)]; }
    else   { src = idx[e];     dst = idx[E + e]; }
    unsigned int pos = (unsigned int)atomicAdd(&cnt[dst], 1);
    rec[e] = ((unsigned int)src << 16) | (pos & 0xFFFFu);
}

// ---- parallel scan (3 kernels) --------------------------------------------
__global__ __launch_bounds__(256) void scanA(const int* __restrict__ cnt,
                                             int* __restrict__ bsum, int N) {
    __shared__ int wt[4];
    int tid = threadIdx.x, lane = tid & 63, w = tid >> 6;
    int i = blockIdx.x * 256 + tid;
    int v = (i < N) ? cnt[i] : 0;
    int s = v;
#pragma unroll
    for (int off = 1; off < 64; off <<= 1) {
        int t = __shfl_up(s, off);
        if (lane >= off) s += t;
    }
    if (lane == 63) wt[w] = s;
    __syncthreads();
    if (tid == 0) bsum[blockIdx.x] = wt[0] + wt[1] + wt[2] + wt[3];
}

__global__ __launch_bounds__(256) void scanB(int* __restrict__ bsum,
                                             int* __restrict__ boff,
                                             int* __restrict__ rowstart,
                                             int nb, int N) {
    __shared__ int wt[4];
    __shared__ int wo[5];
    int tid = threadIdx.x, lane = tid & 63, w = tid >> 6;
    int v = (tid < nb) ? bsum[tid] : 0;
    int s = v;
#pragma unroll
    for (int off = 1; off < 64; off <<= 1) {
        int t = __shfl_up(s, off);
        if (lane >= off) s += t;
    }
    if (lane == 63) wt[w] = s;
    __syncthreads();
    if (tid == 0) {
        int run = 0;
#pragma unroll
        for (int k = 0; k < 4; ++k) { wo[k] = run; run += wt[k]; }
        wo[4] = run;
    }
    __syncthreads();
    if (tid < nb) boff[tid] = wo[w] + s - v;
    if (tid == 0) rowstart[N] = wo[4];
}

__global__ __launch_bounds__(256) void scanC(const int* __restrict__ cnt,
                                             const int* __restrict__ boff,
                                             int* __restrict__ rowstart,
                                             float* __restrict__ dinv, int N) {
    __shared__ int wt[4];
    __shared__ int wo[4];
    int tid = threadIdx.x, lane = tid & 63, w = tid >> 6;
    int i = blockIdx.x * 256 + tid;
    int v = (i < N) ? cnt[i] : 0;
    int s = v;
#pragma unroll
    for (int off = 1; off < 64; off <<= 1) {
        int t = __shfl_up(s, off);
        if (lane >= off) s += t;
    }
    if (lane == 63) wt[w] = s;
    __syncthreads();
    if (tid == 0) {
        int run = 0;
#pragma unroll
        for (int k = 0; k < 4; ++k) { wo[k] = run; run += wt[k]; }
    }
    __syncthreads();
    if (i < N) {
        rowstart[i] = boff[blockIdx.x] + wo[w] + (s - v);
        dinv[i] = rsqrtf(1.0f + (float)v);
    }
}

// ---- pass 2: place src (ushort) at rowstart[dst]+pos, no atomics -----------
__global__ void fill_place(const int* __restrict__ idx, const int* __restrict__ flag,
                           const unsigned int* __restrict__ rec,
                           const int* __restrict__ rowstart,
                           unsigned short* __restrict__ srcs, int E) {
    int e = blockIdx.x * blockDim.x + threadIdx.x;
    if (e >= E) return;
    int f = *flag;
    int dst = f ? idx[2 * (E + e)] : idx[E + e];
    unsigned int r = rec[e];
    srcs[rowstart[dst] + (int)(r & 0xFFFFu)] = (unsigned short)(r >> 16);
}

// ---- pack W[128,128] f32 -> B-fragment-ordered bf16; block b packs Wsrc[b] --
// slot s = (ct*4+kb)*64 + l ; lane l holds B[k=kb*32+(l>>4)*8 + e][col=ct*16+(l&15)]
__global__ __launch_bounds__(256) void pack_w2(const float* __restrict__ W0,
                                               const float* __restrict__ W1,
                                               uint4* __restrict__ wpk0,
                                               uint4* __restrict__ wpk1) {
    const float* W = blockIdx.x ? W1 : W0;
    uint4* wpk = blockIdx.x ? wpk1 : wpk0;
    int tid = threadIdx.x;
    for (int it = 0; it < 8; ++it) {
        int s = it * 256 + tid;            // 2048 slots
        int ct = s >> 8;
        int kb = (s >> 6) & 3;
        int l  = s & 63;
        int col = ct * 16 + (l & 15);
        int k0  = kb * 32 + ((l >> 4) << 3);
        unsigned short e0 = f2b(W[(k0 + 0) * 128 + col]);
        unsigned short e1 = f2b(W[(k0 + 1) * 128 + col]);
        unsigned short e2 = f2b(W[(k0 + 2) * 128 + col]);
        unsigned short e3 = f2b(W[(k0 + 3) * 128 + col]);
        unsigned short e4 = f2b(W[(k0 + 4) * 128 + col]);
        unsigned short e5 = f2b(W[(k0 + 5) * 128 + col]);
        unsigned short e6 = f2b(W[(k0 + 6) * 128 + col]);
        unsigned short e7 = f2b(W[(k0 + 7) * 128 + col]);
        uint4 u;
        u.x = (unsigned int)e0 | ((unsigned int)e1 << 16);
        u.y = (unsigned int)e2 | ((unsigned int)e3 << 16);
        u.z = (unsigned int)e4 | ((unsigned int)e5 << 16);
        u.w = (unsigned int)e6 | ((unsigned int)e7 << 16);
        wpk[s] = u;
    }
}

// ---- MFMA GEMM: out_bf16[N,128] = A[N,128] @ W(packed) ---------------------
// 128 rows/block: wave w owns row-tiles {blk*128 + w*16, blk*128 + 64 + w*16}.
// B-frag loaded once per (ct,kb), reused for both tiles.
template <int ABF>
__global__ __launch_bounds__(256) void gemm_mfma(const void* __restrict__ Ap,
                                                 const uint4* __restrict__ wpk,
                                                 unsigned short* __restrict__ outb,
                                                 int N) {
    __shared__ unsigned short ol[128 * 128];   // 32KB epilogue bounce
    int tid = threadIdx.x;
    int w = tid >> 6, l = tid & 63;
    int lr = l & 15, lq = l >> 4;
    int base = blockIdx.x * 128;
    int arow0 = base + w * 16 + lr;
    int arow1 = base + 64 + w * 16 + lr;
    int ar0 = (arow0 < N) ? arow0 : (N - 1);
    int ar1 = (arow1 < N) ? arow1 : (N - 1);

    float4v acc[2][8];
#pragma unroll
    for (int t = 0; t < 2; ++t)
#pragma unroll
        for (int ct = 0; ct < 8; ++ct) acc[t][ct] = (float4v){0.f, 0.f, 0.f, 0.f};

#pragma unroll
    for (int kb = 0; kb < 4; ++kb) {
        short8v af0, af1;
        if (ABF) {
            uint4 v0 = *(const uint4*)((const unsigned short*)Ap + (size_t)ar0 * 128 + kb * 32 + lq * 8);
            uint4 v1 = *(const uint4*)((const unsigned short*)Ap + (size_t)ar1 * 128 + kb * 32 + lq * 8);
            union { uint4 u; short8v s; } c0, c1; c0.u = v0; c1.u = v1;
            af0 = c0.s; af1 = c1.s;
        } else {
            const float* a0 = (const float*)Ap + (size_t)ar0 * 128 + kb * 32 + lq * 8;
            const float* a1 = (const float*)Ap + (size_t)ar1 * 128 + kb * 32 + lq * 8;
            float4 va0 = *(const float4*)a0, vb0 = *(const float4*)(a0 + 4);
            float4 va1 = *(const float4*)a1, vb1 = *(const float4*)(a1 + 4);
            uint4 u0, u1;
            u0.x = (unsigned int)f2b(va0.x) | ((unsigned int)f2b(va0.y) << 16);
            u0.y = (unsigned int)f2b(va0.z) | ((unsigned int)f2b(va0.w) << 16);
            u0.z = (unsigned int)f2b(vb0.x) | ((unsigned int)f2b(vb0.y) << 16);
            u0.w = (unsigned int)f2b(vb0.z) | ((unsigned int)f2b(vb0.w) << 16);
            u1.x = (unsigned int)f2b(va1.x) | ((unsigned int)f2b(va1.y) << 16);
            u1.y = (unsigned int)f2b(va1.z) | ((unsigned int)f2b(va1.w) << 16);
            u1.z = (unsigned int)f2b(vb1.x) | ((unsigned int)f2b(vb1.y) << 16);
            u1.w = (unsigned int)f2b(vb1.z) | ((unsigned int)f2b(vb1.w) << 16);
            union { uint4 uu; short8v s; } c0, c1; c0.uu = u0; c1.uu = u1;
            af0 = c0.s; af1 = c1.s;
        }
#pragma unroll
        for (int ct = 0; ct < 8; ++ct) {
            uint4 bv = wpk[(ct * 4 + kb) * 64 + l];
            union { uint4 u; short8v s; } cv; cv.u = bv; short8v bf = cv.s;
            acc[0][ct] = __builtin_amdgcn_mfma_f32_16x16x32_bf16(af0, bf, acc[0][ct], 0, 0, 0);
            acc[1][ct] = __builtin_amdgcn_mfma_f32_16x16x32_bf16(af1, bf, acc[1][ct], 0, 0, 0);
        }
    }

    // epilogue: D -> LDS (bf16) -> coalesced global store
#pragma unroll
    for (int t = 0; t < 2; ++t)
#pragma unroll
        for (int ct = 0; ct < 8; ++ct)
#pragma unroll
            for (int r = 0; r < 4; ++r)
                ol[(t * 64 + w * 16 + lq * 4 + r) * 128 + ct * 16 + lr] = f2b(acc[t][ct][r]);
    __syncthreads();
#pragma unroll
    for (int it = 0; it < 8; ++it) {
        int o = it * 4096 + tid * 16;        // byte offset into ol
        int rr = o >> 8;                      // local row (256B per row)
        int cb = o & 255;
        int gr = base + rr;
        if (gr < N) {
            uint4 v = *(const uint4*)((const char*)ol + o);
            *(uint4*)((char*)outb + (size_t)gr * 256 + cb) = v;
        }
    }
}

// ---- aggregation: one wave/node, 8 edges in flight per inner iteration -----
// 16 lanes per edge (quarter = lane>>4), each lane 16B = 8 features.
__global__ __launch_bounds__(256) void agg_node(const unsigned short* __restrict__ hb,
                                                const int* __restrict__ rowstart,
                                                const unsigned short* __restrict__ srcs,
                                                const float* __restrict__ dinv,
                                                const float* __restrict__ b,
                                                unsigned short* __restrict__ outb,
                                                int N, int do_relu) {
    int w = threadIdx.x >> 6, lane = threadIdx.x & 63;
    int node = blockIdx.x * 4 + w;
    if (node >= N) return;
    int beg = rowstart[node], end = rowstart[node + 1];
    float dn = dinv[node];
    int quarter = lane >> 4, q = lane & 15;
    const uint4* hb8 = (const uint4*)hb;   // 8 bf16 per uint4
    float a0 = 0.f, a1 = 0.f, a2 = 0.f, a3 = 0.f;
    float a4 = 0.f, a5 = 0.f, a6 = 0.f, a7 = 0.f;

    for (int j0 = beg; j0 < end; j0 += 64) {
        int myj = j0 + lane;
        int ms = 0;
        float md = 0.f;
        if (myj < end) { ms = (int)srcs[myj]; md = dinv[ms]; }
        int m = min(64, end - j0);
#pragma unroll 2
        for (int k = 0; k < m; k += 8) {
            int i0 = k + quarter;
            int i1 = k + 4 + quarter;        // may exceed m on tails: c1=0 there
            int s0 = __shfl(ms, i0);
            int s1 = __shfl(ms, i1);
            float c0 = dn * __shfl(md, i0);
            float c1 = dn * __shfl(md, i1);
            uint4 v0 = hb8[(size_t)s0 * 16 + q];
            uint4 v1 = hb8[(size_t)s1 * 16 + q];
            a0 += c0 * b2f(v0.x & 0xFFFFu);
            a1 += c0 * b2f(v0.x >> 16);
            a2 += c0 * b2f(v0.y & 0xFFFFu);
            a3 += c0 * b2f(v0.y >> 16);
            a4 += c0 * b2f(v0.z & 0xFFFFu);
            a5 += c0 * b2f(v0.z >> 16);
            a6 += c0 * b2f(v0.w & 0xFFFFu);
            a7 += c0 * b2f(v0.w >> 16);
            a0 += c1 * b2f(v1.x & 0xFFFFu);
            a1 += c1 * b2f(v1.x >> 16);
            a2 += c1 * b2f(v1.y & 0xFFFFu);
            a3 += c1 * b2f(v1.y >> 16);
            a4 += c1 * b2f(v1.z & 0xFFFFu);
            a5 += c1 * b2f(v1.z >> 16);
            a6 += c1 * b2f(v1.w & 0xFFFFu);
            a7 += c1 * b2f(v1.w >> 16);
        }
    }
    a0 += __shfl_xor(a0, 32); a1 += __shfl_xor(a1, 32);
    a2 += __shfl_xor(a2, 32); a3 += __shfl_xor(a3, 32);
    a4 += __shfl_xor(a4, 32); a5 += __shfl_xor(a5, 32);
    a6 += __shfl_xor(a6, 32); a7 += __shfl_xor(a7, 32);
    a0 += __shfl_xor(a0, 16); a1 += __shfl_xor(a1, 16);
    a2 += __shfl_xor(a2, 16); a3 += __shfl_xor(a3, 16);
    a4 += __shfl_xor(a4, 16); a5 += __shfl_xor(a5, 16);
    a6 += __shfl_xor(a6, 16); a7 += __shfl_xor(a7, 16);

    if (quarter == 0) {
        uint4 sv = hb8[(size_t)node * 16 + q];
        float d2 = dn * dn;
        float4 b0 = ((const float4*)b)[2 * q];
        float4 b1 = ((const float4*)b)[2 * q + 1];
        float r0 = a0 + d2 * b2f(sv.x & 0xFFFFu) + b0.x;
        float r1 = a1 + d2 * b2f(sv.x >> 16)     + b0.y;
        float r2 = a2 + d2 * b2f(sv.y & 0xFFFFu) + b0.z;
        float r3 = a3 + d2 * b2f(sv.y >> 16)     + b0.w;
        float r4 = a4 + d2 * b2f(sv.z & 0xFFFFu) + b1.x;
        float r5 = a5 + d2 * b2f(sv.z >> 16)     + b1.y;
        float r6 = a6 + d2 * b2f(sv.w & 0xFFFFu) + b1.z;
        float r7 = a7 + d2 * b2f(sv.w >> 16)     + b1.w;
        if (do_relu) {
            r0 = fmaxf(r0, 0.f); r1 = fmaxf(r1, 0.f);
            r2 = fmaxf(r2, 0.f); r3 = fmaxf(r3, 0.f);
            r4 = fmaxf(r4, 0.f); r5 = fmaxf(r5, 0.f);
            r6 = fmaxf(r6, 0.f); r7 = fmaxf(r7, 0.f);
        }
        uint4 o;
        o.x = (unsigned int)f2b(r0) | ((unsigned int)f2b(r1) << 16);
        o.y = (unsigned int)f2b(r2) | ((unsigned int)f2b(r3) << 16);
        o.z = (unsigned int)f2b(r4) | ((unsigned int)f2b(r5) << 16);
        o.w = (unsigned int)f2b(r6) | ((unsigned int)f2b(r7) << 16);
        ((uint4*)outb)[(size_t)node * 16 + q] = o;
    }
}

// ---- output: out[N,40] = log_softmax(h2 @ W_out + b_out) -------------------
__global__ __launch_bounds__(256) void out_gemm(const unsigned short* __restrict__ h2b,
                                                const float* __restrict__ Wout,
                                                const float* __restrict__ bout,
                                                float* __restrict__ out, int N) {
    __shared__ float Xt[128 * 128];  // Xt[k][r], f32
    __shared__ float Wl[128 * 40];
    __shared__ float bl[40];
    int tid = threadIdx.x;
    int row0 = blockIdx.x * 128;

    for (int i = tid; i < 128 * 40; i += 256) Wl[i] = Wout[i];
    if (tid < 40) bl[tid] = bout[tid];

    {
        int r = tid >> 1, kh = tid & 1;
        int gr = row0 + r;
#pragma unroll
        for (int i = 0; i < 16; ++i) {
            int k = kh * 64 + i * 4;
            float f0, f1, f2, f3;
            if (gr < N) {
                uint2 qv = ((const uint2*)h2b)[(size_t)gr * 32 + (k >> 2)];
                f0 = b2f(qv.x & 0xFFFFu); f1 = b2f(qv.x >> 16);
                f2 = b2f(qv.y & 0xFFFFu); f3 = b2f(qv.y >> 16);
            } else {
                f0 = f1 = f2 = f3 = 0.f;
            }
            Xt[(k + 0) * 128 + r] = f0;
            Xt[(k + 1) * 128 + r] = f1;
            Xt[(k + 2) * 128 + r] = f2;
            Xt[(k + 3) * 128 + r] = f3;
        }
    }
    __syncthreads();

    int cg = tid & 7;    // cols 5cg..5cg+4
    int r4 = tid >> 3;   // rows r4*4..r4*4+3
    float bias[5];
#pragma unroll
    for (int c = 0; c < 5; ++c) bias[c] = bl[5 * cg + c];

    float acc[4][5];
#pragma unroll
    for (int j = 0; j < 4; ++j)
#pragma unroll
        for (int c = 0; c < 5; ++c) acc[j][c] = 0.f;

    const float4* Xt4 = (const float4*)Xt;
#pragma unroll 4
    for (int k = 0; k < 128; ++k) {
        float4 xv = Xt4[k * 32 + r4];
        const float* wr = &Wl[k * 40 + 5 * cg];
        float w0 = wr[0], w1 = wr[1], w2 = wr[2], w3 = wr[3], w4 = wr[4];
        float xs[4] = {xv.x, xv.y, xv.z, xv.w};
#pragma unroll
        for (int j = 0; j < 4; ++j) {
            acc[j][0] += xs[j] * w0;
            acc[j][1] += xs[j] * w1;
            acc[j][2] += xs[j] * w2;
            acc[j][3] += xs[j] * w3;
            acc[j][4] += xs[j] * w4;
        }
    }

#pragma unroll
    for (int j = 0; j < 4; ++j) {
        int r = row0 + r4 * 4 + j;
        if (r >= N) continue;   // uniform across the 8-lane shfl group (same r4)
        float v[5];
        float m = -INFINITY;
#pragma unroll
        for (int c = 0; c < 5; ++c) { v[c] = acc[j][c] + bias[c]; m = fmaxf(m, v[c]); }
        m = fmaxf(m, __shfl_xor(m, 1));
        m = fmaxf(m, __shfl_xor(m, 2));
        m = fmaxf(m, __shfl_xor(m, 4));
        float s = 0.f;
#pragma unroll
        for (int c = 0; c < 5; ++c) s += expf(v[c] - m);
        s += __shfl_xor(s, 1);
        s += __shfl_xor(s, 2);
        s += __shfl_xor(s, 4);
        float ls = logf(s);
#pragma unroll
        for (int c = 0; c < 5; ++c) out[(size_t)r * 40 + 5 * cg + c] = v[c] - m - ls;
    }
}

static inline size_t al256(size_t x) { return (x + 255) & ~(size_t)255; }

extern "C" void kernel_launch(void* const* d_in, const int* in_sizes, int n_in,
                              void* d_out, int out_size, void* d_ws, size_t ws_size,
                              hipStream_t stream) {
    const float* x     = (const float*)d_in[0];
    const int*   idx   = (const int*)d_in[1];
    const float* W_in  = (const float*)d_in[2];
    const float* b_in  = (const float*)d_in[3];
    const float* W1    = (const float*)d_in[4];
    const float* b1    = (const float*)d_in[5];
    const float* W_out = (const float*)d_in[6];
    const float* b_out = (const float*)d_in[7];
    float* out = (float*)d_out;

    int N = in_sizes[0] / 128;
    int E = in_sizes[1] / 2;

    char* ws = (char*)d_ws;
    size_t off = 0;
    int* flag = (int*)(ws + off);              off += 256;
    int* cnt = (int*)(ws + off);               off += al256((size_t)N * 4);
    int* rowstart = (int*)(ws + off);          off += al256((size_t)(N + 1) * 4);
    float* dinv = (float*)(ws + off);          off += al256((size_t)N * 4);
    unsigned short* srcs = (unsigned short*)(ws + off); off += al256((size_t)E * 2);
    unsigned int* rec = (unsigned int*)(ws + off);      off += al256((size_t)E * 4);
    int* bsum = (int*)(ws + off);              off += 2048;
    int* boff = (int*)(ws + off);              off += 2048;
    uint4* wpk1 = (uint4*)(ws + off);          off += 32768;   // packed W_in
    uint4* wpk2 = (uint4*)(ws + off);          off += 32768;   // packed W1
    unsigned short* B0 = (unsigned short*)(ws + off);   off += (size_t)N * 128 * 2;
    unsigned short* B1 = (unsigned short*)(ws + off);

    int nb_e = (E + THREADS - 1) / THREADS;
    int nb_n = (N + THREADS - 1) / THREADS;   // scan blocks (<=256 for N<=65536)
    int nb_g = (N + 127) / 128;
    int nb_a = (N + 3) / 4;

    detect_idx64<<<1, 64, 0, stream>>>(idx, flag);
    hipMemsetAsync(cnt, 0, (size_t)N * 4, stream);
    pack_w2<<<2, THREADS, 0, stream>>>(W_in, W1, wpk1, wpk2);
    fill_pos<<<nb_e, THREADS, 0, stream>>>(idx, flag, cnt, rec, E);
    scanA<<<nb_n, THREADS, 0, stream>>>(cnt, bsum, N);
    scanB<<<1, THREADS, 0, stream>>>(bsum, boff, rowstart, nb_n, N);
    scanC<<<nb_n, THREADS, 0, stream>>>(cnt, boff, rowstart, dinv, N);
    fill_place<<<nb_e, THREADS, 0, stream>>>(idx, flag, rec, rowstart, srcs, E);

    // layer 1
    gemm_mfma<0><<<nb_g, THREADS, 0, stream>>>(x, wpk1, B0, N);               // h0
    agg_node<<<nb_a, THREADS, 0, stream>>>(B0, rowstart, srcs, dinv, b_in,
                                           B1, N, 0);                         // h1
    // layer 2
    gemm_mfma<1><<<nb_g, THREADS, 0, stream>>>(B1, wpk2, B0, N);              // t
    agg_node<<<nb_a, THREADS, 0, stream>>>(B0, rowstart, srcs, dinv, b1,
                                           B1, N, 1);                         // h2
    // output layer + fused log_softmax
    out_gemm<<<nb_g, THREADS, 0, stream>>>(B1, W_out, b_out, out, N);
}